// Round 1
// baseline (2529.580 us; speedup 1.0000x reference)
//
#include <hip/hip_runtime.h>
#include <cstdint>

// GAT 3-layer forward for MI355X.
// Layers 0/1: 128 -> (2 heads x 64), concat + ELU. Layer 2: 128 -> 40, softmax.
// Softmax-over-edges computed WITHOUT segment_max (mathematically identical,
// |e| <~ 10 so exp() is safe in fp32). Self-loops folded analytically into
// denom init (att_dot epilogue) and out init (self_agg), so no edge-list
// append and no memsets are needed.

#define DEV __device__ __forceinline__

DEV float lrelu(float v) { return v > 0.f ? v : 0.2f * v; }

DEV void fma4(float4& a, float s, const float4& w) {
  a.x = fmaf(s, w.x, a.x); a.y = fmaf(s, w.y, a.y);
  a.z = fmaf(s, w.z, a.z); a.w = fmaf(s, w.w, a.w);
}

// ---- GEMM: [Nn,128] @ [128,128] -> [Nn,128]. 64-node tile, x in LDS. ----
__global__ __launch_bounds__(256) void k_linear128(
    const float* __restrict__ X, const float* __restrict__ W,
    float* __restrict__ Hb, int Nn)
{
  __shared__ float xs[64 * 128];
  int n0 = blockIdx.x * 64;
  int valid = Nn - n0;
  const float* xsrc = X + (size_t)n0 * 128;
  if (valid >= 64) {
    for (int i = threadIdx.x; i < 64 * 128; i += 256) xs[i] = xsrc[i];
  } else {
    for (int i = threadIdx.x; i < 64 * 128; i += 256)
      xs[i] = (i < valid * 128) ? xsrc[i] : 0.f;
  }
  __syncthreads();
  int cg = threadIdx.x & 31;   // cols cg*4 .. cg*4+3
  int ng = threadIdx.x >> 5;   // nodes ng*8 .. +8
  float4 acc[8];
#pragma unroll
  for (int i = 0; i < 8; ++i) acc[i] = make_float4(0.f, 0.f, 0.f, 0.f);
  const float* wp = W + cg * 4;
  for (int k = 0; k < 128; k += 4) {
    float4 w0 = *(const float4*)(wp + (k + 0) * 128);
    float4 w1 = *(const float4*)(wp + (k + 1) * 128);
    float4 w2 = *(const float4*)(wp + (k + 2) * 128);
    float4 w3 = *(const float4*)(wp + (k + 3) * 128);
#pragma unroll
    for (int i = 0; i < 8; ++i) {
      float4 xv = *(const float4*)&xs[(ng * 8 + i) * 128 + k];
      fma4(acc[i], xv.x, w0); fma4(acc[i], xv.y, w1);
      fma4(acc[i], xv.z, w2); fma4(acc[i], xv.w, w3);
    }
  }
#pragma unroll
  for (int i = 0; i < 8; ++i) {
    int n = n0 + ng * 8 + i;
    if (n < Nn) *(float4*)&Hb[(size_t)n * 128 + cg * 4] = acc[i];
  }
}

// ---- GEMM: [Nn,128] @ [128,40] -> [Nn,40] (layer 2) ----
__global__ __launch_bounds__(256) void k_linear40(
    const float* __restrict__ X, const float* __restrict__ W,
    float* __restrict__ Hb, int Nn)
{
  __shared__ float xs[64 * 128];
  int n0 = blockIdx.x * 64;
  int valid = Nn - n0;
  const float* xsrc = X + (size_t)n0 * 128;
  if (valid >= 64) {
    for (int i = threadIdx.x; i < 64 * 128; i += 256) xs[i] = xsrc[i];
  } else {
    for (int i = threadIdx.x; i < 64 * 128; i += 256)
      xs[i] = (i < valid * 128) ? xsrc[i] : 0.f;
  }
  __syncthreads();
  int cg = threadIdx.x & 15;           // col group; active if < 10 (40 cols)
  int ng = threadIdx.x >> 4;           // nodes ng*4 .. +4
  int cgc = cg < 10 ? cg : 9;          // clamp so OOB lanes read valid W
  float4 acc[4];
#pragma unroll
  for (int i = 0; i < 4; ++i) acc[i] = make_float4(0.f, 0.f, 0.f, 0.f);
  const float* wp = W + cgc * 4;
  for (int k = 0; k < 128; k += 4) {
    float4 w0 = *(const float4*)(wp + (k + 0) * 40);
    float4 w1 = *(const float4*)(wp + (k + 1) * 40);
    float4 w2 = *(const float4*)(wp + (k + 2) * 40);
    float4 w3 = *(const float4*)(wp + (k + 3) * 40);
#pragma unroll
    for (int i = 0; i < 4; ++i) {
      float4 xv = *(const float4*)&xs[(ng * 4 + i) * 128 + k];
      fma4(acc[i], xv.x, w0); fma4(acc[i], xv.y, w1);
      fma4(acc[i], xv.z, w2); fma4(acc[i], xv.w, w3);
    }
  }
  if (cg < 10) {
#pragma unroll
    for (int i = 0; i < 4; ++i) {
      int n = n0 + ng * 4 + i;
      if (n < Nn) *(float4*)&Hb[(size_t)n * 40 + cg * 4] = acc[i];
    }
  }
}

// ---- per-node attention dots; fused denom init with self-loop exp term ----
template<int H, int C>
__global__ __launch_bounds__(256) void k_att_dot(
    const float* __restrict__ Hb, const float* __restrict__ avs,
    const float* __restrict__ avd, float* __restrict__ asrc,
    float* __restrict__ adst, float* __restrict__ denom, int Nn)
{
  int wid = (blockIdx.x * 256 + threadIdx.x) >> 6;   // wave per node
  int lane = threadIdx.x & 63;
  if (wid >= Nn) return;
  const float* hrow = Hb + (size_t)wid * (H * C);
#pragma unroll
  for (int hd = 0; hd < H; ++hd) {
    float s = 0.f, d = 0.f;
    if (lane < C) {
      float hv = hrow[hd * C + lane];
      s = hv * avs[hd * C + lane];
      d = hv * avd[hd * C + lane];
    }
#pragma unroll
    for (int off = 32; off; off >>= 1) {
      s += __shfl_xor(s, off);
      d += __shfl_xor(d, off);
    }
    if (lane == 0) {
      asrc[wid * H + hd] = s;
      adst[wid * H + hd] = d;
      denom[wid * H + hd] = expf(lrelu(s + d));  // self-loop contribution
    }
  }
}

// ---- accumulate exp(e) into softmax denominators over real edges ----
template<int H>
__global__ __launch_bounds__(256) void k_edge_denom(
    const int* __restrict__ ei, const float* __restrict__ asrc,
    const float* __restrict__ adst, float* __restrict__ denom, int E)
{
  int e = blockIdx.x * 256 + threadIdx.x;
  if (e >= E) return;
  int s = ei[e], d = ei[E + e];
#pragma unroll
  for (int hd = 0; hd < H; ++hd) {
    float v = lrelu(asrc[s * H + hd] + adst[d * H + hd]);
    atomicAdd(&denom[d * H + hd], expf(v));
  }
}

// ---- init out with the self-loop message (plain store, no atomic) ----
template<int H, int C>
__global__ __launch_bounds__(256) void k_self_agg(
    const float* __restrict__ Hb, const float* __restrict__ asrc,
    const float* __restrict__ adst, const float* __restrict__ denom,
    float* __restrict__ out, int Nn)
{
  constexpr int HC = H * C;
  int i = blockIdx.x * 256 + threadIdx.x;
  if (i >= Nn * HC) return;
  int n = i / HC, hc = i % HC;
  int hd = hc / C;
  float v = lrelu(asrc[n * H + hd] + adst[n * H + hd]);
  float alpha = expf(v) / denom[n * H + hd];
  out[i] = Hb[i] * alpha;
}

// ---- scatter-add weighted messages over real edges ----
template<int H, int C, int TPE>
__global__ __launch_bounds__(256) void k_edge_agg(
    const int* __restrict__ ei, const float* __restrict__ Hb,
    const float* __restrict__ asrc, const float* __restrict__ adst,
    const float* __restrict__ denom, float* __restrict__ out, int E)
{
  constexpr int HC = H * C;
  int gid = blockIdx.x * 256 + threadIdx.x;
  int e = gid / TPE, t = gid % TPE;
  if (e >= E) return;
  if (TPE > HC && t >= HC) return;
  int s = ei[e], d = ei[E + e];
  int hd = t / C;
  float v = lrelu(asrc[s * H + hd] + adst[d * H + hd]);
  float alpha = expf(v) / denom[d * H + hd];
  atomicAdd(&out[(size_t)d * HC + t], Hb[(size_t)s * HC + t] * alpha);
}

// ---- bias + ELU in place (HC == 128 for layers 0/1) ----
__global__ __launch_bounds__(256) void k_post_elu(
    float* __restrict__ io, const float* __restrict__ b, int total)
{
  int i = blockIdx.x * 256 + threadIdx.x;
  if (i >= total) return;
  float v = io[i] + b[i & 127];
  io[i] = v > 0.f ? v : expm1f(v);
}

// ---- bias + row softmax over 40 classes -> d_out ----
__global__ __launch_bounds__(256) void k_post_softmax(
    const float* __restrict__ in, const float* __restrict__ b2,
    float* __restrict__ out, int Nn)
{
  int wid = (blockIdx.x * 256 + threadIdx.x) >> 6;
  int lane = threadIdx.x & 63;
  if (wid >= Nn) return;
  float v = (lane < 40) ? in[wid * 40 + lane] + b2[lane] : -3.4e38f;
  float m = v;
#pragma unroll
  for (int off = 32; off; off >>= 1) m = fmaxf(m, __shfl_xor(m, off));
  float ex = (lane < 40) ? expf(v - m) : 0.f;
  float ssum = ex;
#pragma unroll
  for (int off = 32; off; off >>= 1) ssum += __shfl_xor(ssum, off);
  if (lane < 40) out[wid * 40 + lane] = ex / ssum;
}

extern "C" void kernel_launch(void* const* d_in, const int* in_sizes, int n_in,
                              void* d_out, int out_size, void* d_ws, size_t ws_size,
                              hipStream_t stream) {
  const float* x   = (const float*)d_in[0];
  const int*   ei  = (const int*)d_in[1];    // [2,E] row-major: src then dst
  const float* W0  = (const float*)d_in[2];
  const float* as0 = (const float*)d_in[3];
  const float* ad0 = (const float*)d_in[4];
  const float* b0  = (const float*)d_in[5];
  const float* W1  = (const float*)d_in[6];
  const float* as1 = (const float*)d_in[7];
  const float* ad1 = (const float*)d_in[8];
  const float* b1  = (const float*)d_in[9];
  const float* W2  = (const float*)d_in[10];
  const float* as2 = (const float*)d_in[11];
  const float* ad2 = (const float*)d_in[12];
  const float* b2  = (const float*)d_in[13];
  float* out = (float*)d_out;

  const int N = in_sizes[0] / 128;
  const int E = in_sizes[1] / 2;

  // workspace: hbuf 51.2MB | obuf 51.2MB | asrc 0.8 | adst 0.8 | denom 0.8
  char* wsb = (char*)d_ws;
  float* hbuf  = (float*)wsb;
  float* obuf  = (float*)(wsb + (size_t)N * 128 * 4);
  float* asrc  = (float*)(wsb + (size_t)N * 128 * 4 * 2);
  float* adst  = asrc + (size_t)N * 2;
  float* denom = adst + (size_t)N * 2;

  dim3 blk(256);
  int g_lin    = (N + 63) / 64;
  int g_wave   = (N + 3) / 4;                              // 1 wave per node
  int g_e128   = (N * 128 + 255) / 256;
  int g_e40    = (N * 40 + 255) / 256;
  int g_edge   = (E + 255) / 256;
  int g_agg128 = (int)(((long long)E * 128 + 255) / 256);
  int g_agg64  = (int)(((long long)E * 64 + 255) / 256);

  // ---------------- layer 0 ----------------
  k_linear128<<<g_lin, blk, 0, stream>>>(x, W0, hbuf, N);
  k_att_dot<2, 64><<<g_wave, blk, 0, stream>>>(hbuf, as0, ad0, asrc, adst, denom, N);
  k_edge_denom<2><<<g_edge, blk, 0, stream>>>(ei, asrc, adst, denom, E);
  k_self_agg<2, 64><<<g_e128, blk, 0, stream>>>(hbuf, asrc, adst, denom, obuf, N);
  k_edge_agg<2, 64, 128><<<g_agg128, blk, 0, stream>>>(ei, hbuf, asrc, adst, denom, obuf, E);
  k_post_elu<<<g_e128, blk, 0, stream>>>(obuf, b0, N * 128);

  // ---------------- layer 1 ----------------
  k_linear128<<<g_lin, blk, 0, stream>>>(obuf, W1, hbuf, N);
  k_att_dot<2, 64><<<g_wave, blk, 0, stream>>>(hbuf, as1, ad1, asrc, adst, denom, N);
  k_edge_denom<2><<<g_edge, blk, 0, stream>>>(ei, asrc, adst, denom, E);
  k_self_agg<2, 64><<<g_e128, blk, 0, stream>>>(hbuf, asrc, adst, denom, obuf, N);
  k_edge_agg<2, 64, 128><<<g_agg128, blk, 0, stream>>>(ei, hbuf, asrc, adst, denom, obuf, E);
  k_post_elu<<<g_e128, blk, 0, stream>>>(obuf, b1, N * 128);

  // ---------------- layer 2 ----------------
  k_linear40<<<g_lin, blk, 0, stream>>>(obuf, W2, hbuf, N);
  k_att_dot<1, 40><<<g_wave, blk, 0, stream>>>(hbuf, as2, ad2, asrc, adst, denom, N);
  k_edge_denom<1><<<g_edge, blk, 0, stream>>>(ei, asrc, adst, denom, E);
  k_self_agg<1, 40><<<g_e40, blk, 0, stream>>>(hbuf, asrc, adst, denom, obuf, N);
  k_edge_agg<1, 40, 64><<<g_agg64, blk, 0, stream>>>(ei, hbuf, asrc, adst, denom, obuf, E);
  k_post_softmax<<<g_wave, blk, 0, stream>>>(obuf, b2, out, N);
}

// Round 2
// 1114.095 us; speedup vs baseline: 2.2705x; 2.2705x over previous
//
#include <hip/hip_runtime.h>
#include <cstdint>

// GAT 3-layer forward for MI355X — round 2.
// Change vs round 1: device-built CSR (counting sort by dst, built once,
// reused by all 3 layers) replaces all fp32 scatter-atomics. Aggregation is
// a per-node wave gather accumulating BOTH the weighted-message numerator and
// the softmax denominator in registers (alpha_i = exp(e_i)/den factors out),
// with bias+ELU / bias+softmax fused into the epilogue.

#define DEV __device__ __forceinline__

DEV float lrelu(float v) { return v > 0.f ? v : 0.2f * v; }

DEV void fma4(float4& a, float s, const float4& w) {
  a.x = fmaf(s, w.x, a.x); a.y = fmaf(s, w.y, a.y);
  a.z = fmaf(s, w.z, a.z); a.w = fmaf(s, w.w, a.w);
}

// ======================= CSR build (once per call) ==========================

__global__ __launch_bounds__(256) void k_zero(int* __restrict__ p, int n) {
  int i = blockIdx.x * 256 + threadIdx.x;
  if (i < n) p[i] = 0;
}

__global__ __launch_bounds__(256) void k_hist(
    const int* __restrict__ ei, int* __restrict__ cnt, int E)
{
  int e = blockIdx.x * 256 + threadIdx.x;
  if (e >= E) return;
  atomicAdd(&cnt[ei[E + e]], 1);
}

// single-workgroup scan: deg (in cursor buf) -> rowptr, and cursor := rowptr
__global__ __launch_bounds__(1024) void k_scan(
    int* __restrict__ degcur, int* __restrict__ rowptr, int Nn)
{
  __shared__ int part[1024];
  int t = threadIdx.x;
  int chunk = (Nn + 1023) >> 10;
  int lo = min(t * chunk, Nn), hi = min(lo + chunk, Nn);
  int s = 0;
  for (int i = lo; i < hi; ++i) s += degcur[i];
  part[t] = s;
  __syncthreads();
  for (int off = 1; off < 1024; off <<= 1) {
    int v = part[t];
    int add = (t >= off) ? part[t - off] : 0;
    __syncthreads();
    part[t] = v + add;
    __syncthreads();
  }
  int base = (t == 0) ? 0 : part[t - 1];
  for (int i = lo; i < hi; ++i) {
    int dv = degcur[i];       // read BEFORE overwrite (degcur aliases cursor)
    rowptr[i] = base;
    degcur[i] = base;         // cursor init
    base += dv;
  }
  if (t == 0) rowptr[Nn] = part[1023];
}

__global__ __launch_bounds__(256) void k_scatter(
    const int* __restrict__ ei, int* __restrict__ cursor,
    int* __restrict__ srt, int E)
{
  int e = blockIdx.x * 256 + threadIdx.x;
  if (e >= E) return;
  int s = ei[e], d = ei[E + e];
  int pos = atomicAdd(&cursor[d], 1);
  srt[pos] = s;
}

// ======================= dense linears ==========================

// [Nn,128] @ [128,128] -> [Nn,128]. 64-node tile, x in LDS.
__global__ __launch_bounds__(256) void k_linear128(
    const float* __restrict__ X, const float* __restrict__ W,
    float* __restrict__ Hb, int Nn)
{
  __shared__ float xs[64 * 128];
  int n0 = blockIdx.x * 64;
  int valid = Nn - n0;
  const float* xsrc = X + (size_t)n0 * 128;
  if (valid >= 64) {
    for (int i = threadIdx.x; i < 64 * 128; i += 256) xs[i] = xsrc[i];
  } else {
    for (int i = threadIdx.x; i < 64 * 128; i += 256)
      xs[i] = (i < valid * 128) ? xsrc[i] : 0.f;
  }
  __syncthreads();
  int cg = threadIdx.x & 31;
  int ng = threadIdx.x >> 5;
  float4 acc[8];
#pragma unroll
  for (int i = 0; i < 8; ++i) acc[i] = make_float4(0.f, 0.f, 0.f, 0.f);
  const float* wp = W + cg * 4;
  for (int k = 0; k < 128; k += 4) {
    float4 w0 = *(const float4*)(wp + (k + 0) * 128);
    float4 w1 = *(const float4*)(wp + (k + 1) * 128);
    float4 w2 = *(const float4*)(wp + (k + 2) * 128);
    float4 w3 = *(const float4*)(wp + (k + 3) * 128);
#pragma unroll
    for (int i = 0; i < 8; ++i) {
      float4 xv = *(const float4*)&xs[(ng * 8 + i) * 128 + k];
      fma4(acc[i], xv.x, w0); fma4(acc[i], xv.y, w1);
      fma4(acc[i], xv.z, w2); fma4(acc[i], xv.w, w3);
    }
  }
#pragma unroll
  for (int i = 0; i < 8; ++i) {
    int n = n0 + ng * 8 + i;
    if (n < Nn) *(float4*)&Hb[(size_t)n * 128 + cg * 4] = acc[i];
  }
}

// [Nn,128] @ [128,40] -> [Nn,40]
__global__ __launch_bounds__(256) void k_linear40(
    const float* __restrict__ X, const float* __restrict__ W,
    float* __restrict__ Hb, int Nn)
{
  __shared__ float xs[64 * 128];
  int n0 = blockIdx.x * 64;
  int valid = Nn - n0;
  const float* xsrc = X + (size_t)n0 * 128;
  if (valid >= 64) {
    for (int i = threadIdx.x; i < 64 * 128; i += 256) xs[i] = xsrc[i];
  } else {
    for (int i = threadIdx.x; i < 64 * 128; i += 256)
      xs[i] = (i < valid * 128) ? xsrc[i] : 0.f;
  }
  __syncthreads();
  int cg = threadIdx.x & 15;
  int ng = threadIdx.x >> 4;
  int cgc = cg < 10 ? cg : 9;
  float4 acc[4];
#pragma unroll
  for (int i = 0; i < 4; ++i) acc[i] = make_float4(0.f, 0.f, 0.f, 0.f);
  const float* wp = W + cgc * 4;
  for (int k = 0; k < 128; k += 4) {
    float4 w0 = *(const float4*)(wp + (k + 0) * 40);
    float4 w1 = *(const float4*)(wp + (k + 1) * 40);
    float4 w2 = *(const float4*)(wp + (k + 2) * 40);
    float4 w3 = *(const float4*)(wp + (k + 3) * 40);
#pragma unroll
    for (int i = 0; i < 4; ++i) {
      float4 xv = *(const float4*)&xs[(ng * 4 + i) * 128 + k];
      fma4(acc[i], xv.x, w0); fma4(acc[i], xv.y, w1);
      fma4(acc[i], xv.z, w2); fma4(acc[i], xv.w, w3);
    }
  }
  if (cg < 10) {
#pragma unroll
    for (int i = 0; i < 4; ++i) {
      int n = n0 + ng * 4 + i;
      if (n < Nn) *(float4*)&Hb[(size_t)n * 40 + cg * 4] = acc[i];
    }
  }
}

// ======================= attention dot products ==========================

template<int H, int C>
__global__ __launch_bounds__(256) void k_att_dot(
    const float* __restrict__ Hb, const float* __restrict__ avs,
    const float* __restrict__ avd, float* __restrict__ asrc,
    float* __restrict__ adst, int Nn)
{
  int wid = (blockIdx.x * 256 + threadIdx.x) >> 6;
  int lane = threadIdx.x & 63;
  if (wid >= Nn) return;
  const float* hrow = Hb + (size_t)wid * (H * C);
#pragma unroll
  for (int hd = 0; hd < H; ++hd) {
    float s = 0.f, d = 0.f;
    if (lane < C) {
      float hv = hrow[hd * C + lane];
      s = hv * avs[hd * C + lane];
      d = hv * avd[hd * C + lane];
    }
#pragma unroll
    for (int off = 32; off; off >>= 1) {
      s += __shfl_xor(s, off);
      d += __shfl_xor(d, off);
    }
    if (lane == 0) {
      asrc[wid * H + hd] = s;
      adst[wid * H + hd] = d;
    }
  }
}

// ======================= fused gather-aggregate ==========================

// layers 0/1: H=2, C=64. One wave per dst node; lane owns channels lane and
// 64+lane. Numerator and denominator accumulate together; bias+ELU fused.
__global__ __launch_bounds__(256) void k_agg128(
    const int* __restrict__ rowptr, const int* __restrict__ srt,
    const float* __restrict__ Hb, const float* __restrict__ asrc,
    const float* __restrict__ adst, const float* __restrict__ bias,
    float* __restrict__ out, int Nn)
{
  int wid = (blockIdx.x * 256 + threadIdx.x) >> 6;
  int lane = threadIdx.x & 63;
  if (wid >= Nn) return;
  float2 ad = *(const float2*)&adst[(size_t)wid * 2];
  float2 as = *(const float2*)&asrc[(size_t)wid * 2];
  // self loop
  float w0 = expf(lrelu(as.x + ad.x)), w1 = expf(lrelu(as.y + ad.y));
  const float* hself = Hb + (size_t)wid * 128;
  float acc0 = w0 * hself[lane], acc1 = w1 * hself[64 + lane];
  float den0 = w0, den1 = w1;
  int beg = rowptr[wid], end = rowptr[wid + 1];
  for (int j0 = beg; j0 < end; j0 += 64) {
    int cnt = min(64, end - j0);
    int myS = 0; float2 myA = make_float2(0.f, 0.f);
    if (j0 + lane < end) {
      myS = srt[j0 + lane];
      myA = *(const float2*)&asrc[(size_t)myS * 2];
    }
    for (int k = 0; k < cnt; ++k) {
      int s = __shfl(myS, k);
      float ax = __shfl(myA.x, k), ay = __shfl(myA.y, k);
      float f0 = expf(lrelu(ax + ad.x));
      float f1 = expf(lrelu(ay + ad.y));
      const float* hp = Hb + (size_t)s * 128;
      acc0 = fmaf(f0, hp[lane], acc0);
      acc1 = fmaf(f1, hp[64 + lane], acc1);
      den0 += f0; den1 += f1;
    }
  }
  float v0 = acc0 / den0 + bias[lane];
  float v1 = acc1 / den1 + bias[64 + lane];
  out[(size_t)wid * 128 + lane]      = v0 > 0.f ? v0 : expm1f(v0);
  out[(size_t)wid * 128 + 64 + lane] = v1 > 0.f ? v1 : expm1f(v1);
}

// layer 2: H=1, C=40, epilogue = bias + row softmax -> final output.
__global__ __launch_bounds__(256) void k_agg40(
    const int* __restrict__ rowptr, const int* __restrict__ srt,
    const float* __restrict__ Hb, const float* __restrict__ asrc,
    const float* __restrict__ adst, const float* __restrict__ b2,
    float* __restrict__ out, int Nn)
{
  int wid = (blockIdx.x * 256 + threadIdx.x) >> 6;
  int lane = threadIdx.x & 63;
  if (wid >= Nn) return;
  float ad = adst[wid];
  float w = expf(lrelu(asrc[wid] + ad));
  float hv = (lane < 40) ? Hb[(size_t)wid * 40 + lane] : 0.f;
  float acc = w * hv;
  float den = w;
  int beg = rowptr[wid], end = rowptr[wid + 1];
  for (int j0 = beg; j0 < end; j0 += 64) {
    int cnt = min(64, end - j0);
    int myS = 0; float myA = 0.f;
    if (j0 + lane < end) {
      myS = srt[j0 + lane];
      myA = asrc[myS];
    }
    for (int k = 0; k < cnt; ++k) {
      int s = __shfl(myS, k);
      float ax = __shfl(myA, k);
      float f = expf(lrelu(ax + ad));
      float g = (lane < 40) ? Hb[(size_t)s * 40 + lane] : 0.f;
      acc = fmaf(f, g, acc);
      den += f;
    }
  }
  float v = (lane < 40) ? acc / den + b2[lane] : -3.4e38f;
  float m = v;
#pragma unroll
  for (int off = 32; off; off >>= 1) m = fmaxf(m, __shfl_xor(m, off));
  float ex = (lane < 40) ? expf(v - m) : 0.f;
  float ssum = ex;
#pragma unroll
  for (int off = 32; off; off >>= 1) ssum += __shfl_xor(ssum, off);
  if (lane < 40) out[(size_t)wid * 40 + lane] = ex / ssum;
}

// ======================= launch ==========================

extern "C" void kernel_launch(void* const* d_in, const int* in_sizes, int n_in,
                              void* d_out, int out_size, void* d_ws, size_t ws_size,
                              hipStream_t stream) {
  const float* x   = (const float*)d_in[0];
  const int*   ei  = (const int*)d_in[1];
  const float* W0  = (const float*)d_in[2];
  const float* as0 = (const float*)d_in[3];
  const float* ad0 = (const float*)d_in[4];
  const float* b0  = (const float*)d_in[5];
  const float* W1  = (const float*)d_in[6];
  const float* as1 = (const float*)d_in[7];
  const float* ad1 = (const float*)d_in[8];
  const float* b1  = (const float*)d_in[9];
  const float* W2  = (const float*)d_in[10];
  const float* as2 = (const float*)d_in[11];
  const float* ad2 = (const float*)d_in[12];
  const float* b2  = (const float*)d_in[13];
  float* out = (float*)d_out;

  const int N = in_sizes[0] / 128;
  const int E = in_sizes[1] / 2;

  // workspace layout (floats unless noted):
  // hbuf[N*128] | obuf[N*128] | asrc[N*2] | adst[N*2] |
  // rowptr[N+1] (int) | cursor[N] (int, doubles as deg) | srt[E] (int)
  char* wsb = (char*)d_ws;
  float* hbuf = (float*)wsb;
  float* obuf = hbuf + (size_t)N * 128;
  float* asrc = obuf + (size_t)N * 128;
  float* adst = asrc + (size_t)N * 2;
  int* rowptr = (int*)(adst + (size_t)N * 2);
  int* cursor = rowptr + (N + 1);
  int* srt    = cursor + N;

  dim3 blk(256);
  int g_lin  = (N + 63) / 64;
  int g_wave = (N + 3) / 4;           // 1 wave per node
  int g_edge = (E + 255) / 256;
  int g_node = (N + 255) / 256;

  // ---- CSR build (edge list is identical for all layers) ----
  k_zero<<<g_node, blk, 0, stream>>>(cursor, N);
  k_hist<<<g_edge, blk, 0, stream>>>(ei, cursor, E);
  k_scan<<<1, 1024, 0, stream>>>(cursor, rowptr, N);
  k_scatter<<<g_edge, blk, 0, stream>>>(ei, cursor, srt, E);

  // ---------------- layer 0 ----------------
  k_linear128<<<g_lin, blk, 0, stream>>>(x, W0, hbuf, N);
  k_att_dot<2, 64><<<g_wave, blk, 0, stream>>>(hbuf, as0, ad0, asrc, adst, N);
  k_agg128<<<g_wave, blk, 0, stream>>>(rowptr, srt, hbuf, asrc, adst, b0, obuf, N);

  // ---------------- layer 1 ----------------
  k_linear128<<<g_lin, blk, 0, stream>>>(obuf, W1, hbuf, N);
  k_att_dot<2, 64><<<g_wave, blk, 0, stream>>>(hbuf, as1, ad1, asrc, adst, N);
  k_agg128<<<g_wave, blk, 0, stream>>>(rowptr, srt, hbuf, asrc, adst, b1, obuf, N);

  // ---------------- layer 2 ----------------
  k_linear40<<<g_lin, blk, 0, stream>>>(obuf, W2, hbuf, N);
  k_att_dot<1, 40><<<g_wave, blk, 0, stream>>>(hbuf, as2, ad2, asrc, adst, N);
  k_agg40<<<g_wave, blk, 0, stream>>>(rowptr, srt, hbuf, asrc, adst, b2, out, N);
}

// Round 5
// 885.317 us; speedup vs baseline: 2.8573x; 1.2584x over previous
//
#include <hip/hip_runtime.h>
#include <cstdint>

// GAT 3-layer forward for MI355X — round 5 (= round 4 resubmitted; GPU
// acquisition timed out before it ever ran).
// vs round 3 (failed): fixed EXEC-mask hazard in k_agg128 — the divergent
// ternary `head ? __shfl(myF.y,k) : __shfl(myF.x,k)` executed ds_bpermute
// with half-wave exec masks; reading from an inactive source lane is
// zero/undefined on CDNA. Now both shuffles run in uniform control flow and
// the select happens afterwards. Everything else identical to round 3
// (hierarchical scan replacing the 233us single-block scan; float2 channel
// mapping; hoisted exp in agg kernels).

#define DEV __device__ __forceinline__
#define SCAN_BS 4096   // elements per scan1 block (256 thr x 16)

DEV float lrelu(float v) { return v > 0.f ? v : 0.2f * v; }

DEV void fma4(float4& a, float s, const float4& w) {
  a.x = fmaf(s, w.x, a.x); a.y = fmaf(s, w.y, a.y);
  a.z = fmaf(s, w.z, a.z); a.w = fmaf(s, w.w, a.w);
}

// ======================= CSR build (once per call) ==========================

__global__ __launch_bounds__(256) void k_zero(int* __restrict__ p, int n) {
  int i = blockIdx.x * 256 + threadIdx.x;
  if (i < n) p[i] = 0;
}

__global__ __launch_bounds__(256) void k_hist(
    const int* __restrict__ ei, int* __restrict__ cnt, int E)
{
  int e = blockIdx.x * 256 + threadIdx.x;
  if (e >= E) return;
  atomicAdd(&cnt[ei[E + e]], 1);
}

// scan1: per-block exclusive scan of deg -> rowptr (block-local) + blockSums
__global__ __launch_bounds__(256) void k_scan1(
    const int* __restrict__ deg, int* __restrict__ rowptr,
    int* __restrict__ blockSums, int Nn)
{
  __shared__ int tsum[256];
  int t = threadIdx.x;
  int lo = blockIdx.x * SCAN_BS + t * 16;
  int vals[16];
  int s = 0;
  if (lo + 16 <= Nn) {
    const int4* p = (const int4*)(deg + lo);
#pragma unroll
    for (int q = 0; q < 4; ++q) {
      int4 v4 = p[q];
      vals[4 * q + 0] = v4.x; vals[4 * q + 1] = v4.y;
      vals[4 * q + 2] = v4.z; vals[4 * q + 3] = v4.w;
      s += v4.x + v4.y + v4.z + v4.w;
    }
  } else {
#pragma unroll
    for (int i = 0; i < 16; ++i) {
      int idx = lo + i;
      vals[i] = (idx < Nn) ? deg[idx] : 0;
      s += vals[i];
    }
  }
  tsum[t] = s;
  __syncthreads();
  for (int off = 1; off < 256; off <<= 1) {
    int v = tsum[t];
    int add = (t >= off) ? tsum[t - off] : 0;
    __syncthreads();
    tsum[t] = v + add;
    __syncthreads();
  }
  int run = (t == 0) ? 0 : tsum[t - 1];
  if (t == 255) blockSums[blockIdx.x] = tsum[255];
#pragma unroll
  for (int i = 0; i < 16; ++i) {
    int idx = lo + i;
    if (idx < Nn) rowptr[idx] = run;
    run += vals[i];
  }
}

// scan2: inclusive scan of block sums (nb <= 1024), writes grand total
__global__ __launch_bounds__(1024) void k_scan2(
    int* __restrict__ bs, int* __restrict__ rowptrN, int nb)
{
  __shared__ int sm[1024];
  int t = threadIdx.x;
  sm[t] = (t < nb) ? bs[t] : 0;
  __syncthreads();
  for (int off = 1; off < 1024; off <<= 1) {
    int u = sm[t];
    int add = (t >= off) ? sm[t - off] : 0;
    __syncthreads();
    sm[t] = u + add;
    __syncthreads();
  }
  if (t < nb) bs[t] = sm[t];
  if (t == 0) *rowptrN = sm[1023];
}

// scan3: add block offsets; cursor := rowptr
__global__ __launch_bounds__(256) void k_scan3(
    const int* __restrict__ bs, int* __restrict__ rowptr,
    int* __restrict__ cursor, int Nn)
{
  int i = blockIdx.x * 256 + threadIdx.x;
  if (i >= Nn) return;
  int b = i / SCAN_BS;
  int off = (b == 0) ? 0 : bs[b - 1];
  int v = rowptr[i] + off;
  rowptr[i] = v;
  cursor[i] = v;
}

__global__ __launch_bounds__(256) void k_scatter(
    const int* __restrict__ ei, int* __restrict__ cursor,
    int* __restrict__ srt, int E)
{
  int e = blockIdx.x * 256 + threadIdx.x;
  if (e >= E) return;
  int s = ei[e], d = ei[E + e];
  int pos = atomicAdd(&cursor[d], 1);
  srt[pos] = s;
}

// ======================= dense linears ==========================

__global__ __launch_bounds__(256) void k_linear128(
    const float* __restrict__ X, const float* __restrict__ W,
    float* __restrict__ Hb, int Nn)
{
  __shared__ float xs[64 * 128];
  int n0 = blockIdx.x * 64;
  int valid = Nn - n0;
  const float* xsrc = X + (size_t)n0 * 128;
  if (valid >= 64) {
    for (int i = threadIdx.x; i < 64 * 128; i += 256) xs[i] = xsrc[i];
  } else {
    for (int i = threadIdx.x; i < 64 * 128; i += 256)
      xs[i] = (i < valid * 128) ? xsrc[i] : 0.f;
  }
  __syncthreads();
  int cg = threadIdx.x & 31;
  int ng = threadIdx.x >> 5;
  float4 acc[8];
#pragma unroll
  for (int i = 0; i < 8; ++i) acc[i] = make_float4(0.f, 0.f, 0.f, 0.f);
  const float* wp = W + cg * 4;
  for (int k = 0; k < 128; k += 4) {
    float4 w0 = *(const float4*)(wp + (k + 0) * 128);
    float4 w1 = *(const float4*)(wp + (k + 1) * 128);
    float4 w2 = *(const float4*)(wp + (k + 2) * 128);
    float4 w3 = *(const float4*)(wp + (k + 3) * 128);
#pragma unroll
    for (int i = 0; i < 8; ++i) {
      float4 xv = *(const float4*)&xs[(ng * 8 + i) * 128 + k];
      fma4(acc[i], xv.x, w0); fma4(acc[i], xv.y, w1);
      fma4(acc[i], xv.z, w2); fma4(acc[i], xv.w, w3);
    }
  }
#pragma unroll
  for (int i = 0; i < 8; ++i) {
    int n = n0 + ng * 8 + i;
    if (n < Nn) *(float4*)&Hb[(size_t)n * 128 + cg * 4] = acc[i];
  }
}

__global__ __launch_bounds__(256) void k_linear40(
    const float* __restrict__ X, const float* __restrict__ W,
    float* __restrict__ Hb, int Nn)
{
  __shared__ float xs[64 * 128];
  int n0 = blockIdx.x * 64;
  int valid = Nn - n0;
  const float* xsrc = X + (size_t)n0 * 128;
  if (valid >= 64) {
    for (int i = threadIdx.x; i < 64 * 128; i += 256) xs[i] = xsrc[i];
  } else {
    for (int i = threadIdx.x; i < 64 * 128; i += 256)
      xs[i] = (i < valid * 128) ? xsrc[i] : 0.f;
  }
  __syncthreads();
  int cg = threadIdx.x & 15;
  int ng = threadIdx.x >> 4;
  int cgc = cg < 10 ? cg : 9;
  float4 acc[4];
#pragma unroll
  for (int i = 0; i < 4; ++i) acc[i] = make_float4(0.f, 0.f, 0.f, 0.f);
  const float* wp = W + cgc * 4;
  for (int k = 0; k < 128; k += 4) {
    float4 w0 = *(const float4*)(wp + (k + 0) * 40);
    float4 w1 = *(const float4*)(wp + (k + 1) * 40);
    float4 w2 = *(const float4*)(wp + (k + 2) * 40);
    float4 w3 = *(const float4*)(wp + (k + 3) * 40);
#pragma unroll
    for (int i = 0; i < 4; ++i) {
      float4 xv = *(const float4*)&xs[(ng * 4 + i) * 128 + k];
      fma4(acc[i], xv.x, w0); fma4(acc[i], xv.y, w1);
      fma4(acc[i], xv.z, w2); fma4(acc[i], xv.w, w3);
    }
  }
  if (cg < 10) {
#pragma unroll
    for (int i = 0; i < 4; ++i) {
      int n = n0 + ng * 4 + i;
      if (n < Nn) *(float4*)&Hb[(size_t)n * 40 + cg * 4] = acc[i];
    }
  }
}

// ======================= attention dot products ==========================

template<int H, int C>
__global__ __launch_bounds__(256) void k_att_dot(
    const float* __restrict__ Hb, const float* __restrict__ avs,
    const float* __restrict__ avd, float* __restrict__ asrc,
    float* __restrict__ adst, int Nn)
{
  int wid = (blockIdx.x * 256 + threadIdx.x) >> 6;
  int lane = threadIdx.x & 63;
  if (wid >= Nn) return;
  const float* hrow = Hb + (size_t)wid * (H * C);
#pragma unroll
  for (int hd = 0; hd < H; ++hd) {
    float s = 0.f, d = 0.f;
    if (lane < C) {
      float hv = hrow[hd * C + lane];
      s = hv * avs[hd * C + lane];
      d = hv * avd[hd * C + lane];
    }
#pragma unroll
    for (int off = 32; off; off >>= 1) {
      s += __shfl_xor(s, off);
      d += __shfl_xor(d, off);
    }
    if (lane == 0) {
      asrc[wid * H + hd] = s;
      adst[wid * H + hd] = d;
    }
  }
}

// ======================= fused gather-aggregate ==========================

// layers 0/1: H=2,C=64. Lane owns channels {2*lane, 2*lane+1}; head = lane>>5.
// NOTE: both __shfl calls MUST be in uniform control flow (full EXEC);
// selecting first and shuffling inside a divergent branch reads inactive
// source lanes -> zero/undefined on CDNA (round-3 bug).
__global__ __launch_bounds__(256) void k_agg128(
    const int* __restrict__ rowptr, const int* __restrict__ srt,
    const float* __restrict__ Hb, const float* __restrict__ asrc,
    const float* __restrict__ adst, const float* __restrict__ bias,
    float* __restrict__ out, int Nn)
{
  int wid = (blockIdx.x * 256 + threadIdx.x) >> 6;
  int lane = threadIdx.x & 63;
  if (wid >= Nn) return;
  int head = lane >> 5;
  float2 ad = *(const float2*)&adst[(size_t)wid * 2];
  float2 as = *(const float2*)&asrc[(size_t)wid * 2];
  float w0 = expf(lrelu(as.x + ad.x)), w1 = expf(lrelu(as.y + ad.y));
  float wSelf = head ? w1 : w0;
  float2 hv = *(const float2*)(Hb + (size_t)wid * 128 + 2 * lane);
  float2 acc = make_float2(wSelf * hv.x, wSelf * hv.y);
  float den = wSelf;
  int beg = rowptr[wid], end = rowptr[wid + 1];
  for (int j0 = beg; j0 < end; j0 += 64) {
    int cnt = min(64, end - j0);
    int myS = 0;
    float2 myF = make_float2(0.f, 0.f);
    if (j0 + lane < end) {
      myS = srt[j0 + lane];
      float2 a = *(const float2*)&asrc[(size_t)myS * 2];
      myF.x = expf(lrelu(a.x + ad.x));
      myF.y = expf(lrelu(a.y + ad.y));
    }
    for (int k = 0; k < cnt; ++k) {
      int s = __shfl(myS, k);
      float fx = __shfl(myF.x, k);          // uniform flow: full EXEC
      float fy = __shfl(myF.y, k);
      float f = head ? fy : fx;
      float2 h = *(const float2*)(Hb + (size_t)s * 128 + 2 * lane);
      acc.x = fmaf(f, h.x, acc.x);
      acc.y = fmaf(f, h.y, acc.y);
      den += f;
    }
  }
  float2 bv = *(const float2*)&bias[2 * lane];
  float v0 = acc.x / den + bv.x;
  float v1 = acc.y / den + bv.y;
  float2 o;
  o.x = v0 > 0.f ? v0 : expm1f(v0);
  o.y = v1 > 0.f ? v1 : expm1f(v1);
  *(float2*)&out[(size_t)wid * 128 + 2 * lane] = o;
}

// layer 2: H=1,C=40; epilogue = bias + row softmax -> final output.
__global__ __launch_bounds__(256) void k_agg40(
    const int* __restrict__ rowptr, const int* __restrict__ srt,
    const float* __restrict__ Hb, const float* __restrict__ asrc,
    const float* __restrict__ adst, const float* __restrict__ b2,
    float* __restrict__ out, int Nn)
{
  int wid = (blockIdx.x * 256 + threadIdx.x) >> 6;
  int lane = threadIdx.x & 63;
  if (wid >= Nn) return;
  float ad = adst[wid];
  float w = expf(lrelu(asrc[wid] + ad));
  float hv = (lane < 40) ? Hb[(size_t)wid * 40 + lane] : 0.f;
  float acc = w * hv;
  float den = w;
  int beg = rowptr[wid], end = rowptr[wid + 1];
  for (int j0 = beg; j0 < end; j0 += 64) {
    int cnt = min(64, end - j0);
    int myS = 0;
    float myF = 0.f;
    if (j0 + lane < end) {
      myS = srt[j0 + lane];
      myF = expf(lrelu(asrc[myS] + ad));
    }
    for (int k = 0; k < cnt; ++k) {
      int s = __shfl(myS, k);
      float f = __shfl(myF, k);
      float g = (lane < 40) ? Hb[(size_t)s * 40 + lane] : 0.f;
      acc = fmaf(f, g, acc);
      den += f;
    }
  }
  float v = (lane < 40) ? acc / den + b2[lane] : -3.4e38f;
  float m = v;
#pragma unroll
  for (int off = 32; off; off >>= 1) m = fmaxf(m, __shfl_xor(m, off));
  float ex = (lane < 40) ? expf(v - m) : 0.f;
  float ssum = ex;
#pragma unroll
  for (int off = 32; off; off >>= 1) ssum += __shfl_xor(ssum, off);
  if (lane < 40) out[(size_t)wid * 40 + lane] = ex / ssum;
}

// ======================= launch ==========================

extern "C" void kernel_launch(void* const* d_in, const int* in_sizes, int n_in,
                              void* d_out, int out_size, void* d_ws, size_t ws_size,
                              hipStream_t stream) {
  const float* x   = (const float*)d_in[0];
  const int*   ei  = (const int*)d_in[1];
  const float* W0  = (const float*)d_in[2];
  const float* as0 = (const float*)d_in[3];
  const float* ad0 = (const float*)d_in[4];
  const float* b0  = (const float*)d_in[5];
  const float* W1  = (const float*)d_in[6];
  const float* as1 = (const float*)d_in[7];
  const float* ad1 = (const float*)d_in[8];
  const float* b1  = (const float*)d_in[9];
  const float* W2  = (const float*)d_in[10];
  const float* as2 = (const float*)d_in[11];
  const float* ad2 = (const float*)d_in[12];
  const float* b2  = (const float*)d_in[13];
  float* out = (float*)d_out;

  const int N = in_sizes[0] / 128;
  const int E = in_sizes[1] / 2;

  // ws: hbuf[N*128] | obuf[N*128] | asrc[N*2] | adst[N*2] |
  //     rowptr[pad(N+1)] | cursor[N] | srt[E] | blockSums[1024]   (ints)
  char* wsb = (char*)d_ws;
  float* hbuf = (float*)wsb;
  float* obuf = hbuf + (size_t)N * 128;
  float* asrc = obuf + (size_t)N * 128;
  float* adst = asrc + (size_t)N * 2;
  int* rowptr = (int*)(adst + (size_t)N * 2);
  int* cursor = rowptr + ((N + 1 + 7) & ~7);   // keep cursor 16B-aligned
  int* srt    = cursor + N;
  int* bsums  = srt + E;

  dim3 blk(256);
  int g_lin  = (N + 63) / 64;
  int g_wave = (N + 3) / 4;                 // 1 wave per node
  int g_edge = (E + 255) / 256;
  int g_node = (N + 255) / 256;
  int nb     = (N + SCAN_BS - 1) / SCAN_BS; // scan1 blocks (<=1024)

  // ---- CSR build (edge list identical across layers) ----
  k_zero<<<g_node, blk, 0, stream>>>(cursor, N);
  k_hist<<<g_edge, blk, 0, stream>>>(ei, cursor, E);
  k_scan1<<<nb, blk, 0, stream>>>(cursor, rowptr, bsums, N);
  k_scan2<<<1, 1024, 0, stream>>>(bsums, rowptr + N, nb);
  k_scan3<<<g_node, blk, 0, stream>>>(bsums, rowptr, cursor, N);
  k_scatter<<<g_edge, blk, 0, stream>>>(ei, cursor, srt, E);

  // ---------------- layer 0 ----------------
  k_linear128<<<g_lin, blk, 0, stream>>>(x, W0, hbuf, N);
  k_att_dot<2, 64><<<g_wave, blk, 0, stream>>>(hbuf, as0, ad0, asrc, adst, N);
  k_agg128<<<g_wave, blk, 0, stream>>>(rowptr, srt, hbuf, asrc, adst, b0, obuf, N);

  // ---------------- layer 1 ----------------
  k_linear128<<<g_lin, blk, 0, stream>>>(obuf, W1, hbuf, N);
  k_att_dot<2, 64><<<g_wave, blk, 0, stream>>>(hbuf, as1, ad1, asrc, adst, N);
  k_agg128<<<g_wave, blk, 0, stream>>>(rowptr, srt, hbuf, asrc, adst, b1, obuf, N);

  // ---------------- layer 2 ----------------
  k_linear40<<<g_lin, blk, 0, stream>>>(obuf, W2, hbuf, N);
  k_att_dot<1, 40><<<g_wave, blk, 0, stream>>>(hbuf, as2, ad2, asrc, adst, N);
  k_agg40<<<g_wave, blk, 0, stream>>>(rowptr, srt, hbuf, asrc, adst, b2, out, N);
}

// Round 8
// 804.015 us; speedup vs baseline: 3.1462x; 1.1011x over previous
//
#include <hip/hip_runtime.h>
#include <hip/hip_fp16.h>
#include <cstdint>

// GAT 3-layer forward for MI355X — round 8 (= round 6 kernel, resubmitted
// after two consecutive GPU acquisition timeouts; it has never executed).
// vs round 5 (885 us):
//  * h-buffers for layers 0/1 stored as fp16 -> per-edge gather in k_agg128
//    halves (256 B/edge), the dominant traffic stream. Layer-2 h and all
//    activations (obuf) remain fp32 for accuracy headroom.
//  * attention dot products fused into the linear epilogues (computed from
//    fp32 GEMM accumulators, 16-lane shfl_xor reduce in uniform flow);
//    deletes all 3 k_att_dot dispatches and halves h write traffic.

#define DEV __device__ __forceinline__
#define SCAN_BS 4096   // elements per scan1 block (256 thr x 16)

DEV float lrelu(float v) { return v > 0.f ? v : 0.2f * v; }

DEV void fma4(float4& a, float s, const float4& w) {
  a.x = fmaf(s, w.x, a.x); a.y = fmaf(s, w.y, a.y);
  a.z = fmaf(s, w.z, a.z); a.w = fmaf(s, w.w, a.w);
}

// ======================= CSR build (once per call) ==========================

__global__ __launch_bounds__(256) void k_zero(int* __restrict__ p, int n) {
  int i = blockIdx.x * 256 + threadIdx.x;
  if (i < n) p[i] = 0;
}

__global__ __launch_bounds__(256) void k_hist(
    const int* __restrict__ ei, int* __restrict__ cnt, int E)
{
  int e = blockIdx.x * 256 + threadIdx.x;
  if (e >= E) return;
  atomicAdd(&cnt[ei[E + e]], 1);
}

__global__ __launch_bounds__(256) void k_scan1(
    const int* __restrict__ deg, int* __restrict__ rowptr,
    int* __restrict__ blockSums, int Nn)
{
  __shared__ int tsum[256];
  int t = threadIdx.x;
  int lo = blockIdx.x * SCAN_BS + t * 16;
  int vals[16];
  int s = 0;
  if (lo + 16 <= Nn) {
    const int4* p = (const int4*)(deg + lo);
#pragma unroll
    for (int q = 0; q < 4; ++q) {
      int4 v4 = p[q];
      vals[4 * q + 0] = v4.x; vals[4 * q + 1] = v4.y;
      vals[4 * q + 2] = v4.z; vals[4 * q + 3] = v4.w;
      s += v4.x + v4.y + v4.z + v4.w;
    }
  } else {
#pragma unroll
    for (int i = 0; i < 16; ++i) {
      int idx = lo + i;
      vals[i] = (idx < Nn) ? deg[idx] : 0;
      s += vals[i];
    }
  }
  tsum[t] = s;
  __syncthreads();
  for (int off = 1; off < 256; off <<= 1) {
    int v = tsum[t];
    int add = (t >= off) ? tsum[t - off] : 0;
    __syncthreads();
    tsum[t] = v + add;
    __syncthreads();
  }
  int run = (t == 0) ? 0 : tsum[t - 1];
  if (t == 255) blockSums[blockIdx.x] = tsum[255];
#pragma unroll
  for (int i = 0; i < 16; ++i) {
    int idx = lo + i;
    if (idx < Nn) rowptr[idx] = run;
    run += vals[i];
  }
}

__global__ __launch_bounds__(1024) void k_scan2(
    int* __restrict__ bs, int* __restrict__ rowptrN, int nb)
{
  __shared__ int sm[1024];
  int t = threadIdx.x;
  sm[t] = (t < nb) ? bs[t] : 0;
  __syncthreads();
  for (int off = 1; off < 1024; off <<= 1) {
    int u = sm[t];
    int add = (t >= off) ? sm[t - off] : 0;
    __syncthreads();
    sm[t] = u + add;
    __syncthreads();
  }
  if (t < nb) bs[t] = sm[t];
  if (t == 0) *rowptrN = sm[1023];
}

__global__ __launch_bounds__(256) void k_scan3(
    const int* __restrict__ bs, int* __restrict__ rowptr,
    int* __restrict__ cursor, int Nn)
{
  int i = blockIdx.x * 256 + threadIdx.x;
  if (i >= Nn) return;
  int b = i / SCAN_BS;
  int off = (b == 0) ? 0 : bs[b - 1];
  int v = rowptr[i] + off;
  rowptr[i] = v;
  cursor[i] = v;
}

__global__ __launch_bounds__(256) void k_scatter(
    const int* __restrict__ ei, int* __restrict__ cursor,
    int* __restrict__ srt, int E)
{
  int e = blockIdx.x * 256 + threadIdx.x;
  if (e >= E) return;
  int s = ei[e], d = ei[E + e];
  int pos = atomicAdd(&cursor[d], 1);
  srt[pos] = s;
}

// ============ linear 128->128 with fused att-dots, fp16 h out ==============
// Thread layout: cg = tid&31 owns cols cg*4..+3, ng = tid>>5 owns 8 nodes.
// Head = cg>=16. Dot reduce: 16-lane shfl_xor groups (uniform flow).
__global__ __launch_bounds__(256) void k_linear128f(
    const float* __restrict__ X, const float* __restrict__ W,
    const float* __restrict__ avs, const float* __restrict__ avd,
    __half* __restrict__ H16, float* __restrict__ asrc,
    float* __restrict__ adst, int Nn)
{
  __shared__ float xs[64 * 128];
  int n0 = blockIdx.x * 64;
  int valid = Nn - n0;
  const float* xsrc = X + (size_t)n0 * 128;
  if (valid >= 64) {
    for (int i = threadIdx.x; i < 64 * 128; i += 256) xs[i] = xsrc[i];
  } else {
    for (int i = threadIdx.x; i < 64 * 128; i += 256)
      xs[i] = (i < valid * 128) ? xsrc[i] : 0.f;
  }
  __syncthreads();
  int cg = threadIdx.x & 31;
  int ng = threadIdx.x >> 5;
  int l  = threadIdx.x & 63;
  float4 acc[8];
#pragma unroll
  for (int i = 0; i < 8; ++i) acc[i] = make_float4(0.f, 0.f, 0.f, 0.f);
  const float* wp = W + cg * 4;
  for (int k = 0; k < 128; k += 4) {
    float4 w0 = *(const float4*)(wp + (k + 0) * 128);
    float4 w1 = *(const float4*)(wp + (k + 1) * 128);
    float4 w2 = *(const float4*)(wp + (k + 2) * 128);
    float4 w3 = *(const float4*)(wp + (k + 3) * 128);
#pragma unroll
    for (int i = 0; i < 8; ++i) {
      float4 xv = *(const float4*)&xs[(ng * 8 + i) * 128 + k];
      fma4(acc[i], xv.x, w0); fma4(acc[i], xv.y, w1);
      fma4(acc[i], xv.z, w2); fma4(acc[i], xv.w, w3);
    }
  }
  // epilogue: fp16 store + fused attention dots
  float4 as4 = *(const float4*)&avs[cg * 4];   // avs is [2][64] flat = 128
  float4 ad4 = *(const float4*)&avd[cg * 4];
#pragma unroll
  for (int i = 0; i < 8; ++i) {
    int n = n0 + ng * 8 + i;
    if (n < Nn) {
      __half2 p0 = __floats2half2_rn(acc[i].x, acc[i].y);
      __half2 p1 = __floats2half2_rn(acc[i].z, acc[i].w);
      __half2* dst = (__half2*)(H16 + (size_t)n * 128 + cg * 4);
      dst[0] = p0; dst[1] = p1;
    }
    float s = acc[i].x * as4.x + acc[i].y * as4.y +
              acc[i].z * as4.z + acc[i].w * as4.w;
    float d = acc[i].x * ad4.x + acc[i].y * ad4.y +
              acc[i].z * ad4.z + acc[i].w * ad4.w;
#pragma unroll
    for (int off = 8; off; off >>= 1) {     // uniform flow: full EXEC
      s += __shfl_xor(s, off);
      d += __shfl_xor(d, off);
    }
    if ((l & 15) == 0 && n < Nn) {
      int head = (l >> 4) & 1;
      asrc[(size_t)n * 2 + head] = s;
      adst[(size_t)n * 2 + head] = d;
    }
  }
}

// ============ linear 128->40 with fused att-dots, fp32 h out ===============
__global__ __launch_bounds__(256) void k_linear40f(
    const float* __restrict__ X, const float* __restrict__ W,
    const float* __restrict__ avs, const float* __restrict__ avd,
    float* __restrict__ H32, float* __restrict__ asrc,
    float* __restrict__ adst, int Nn)
{
  __shared__ float xs[64 * 128];
  int n0 = blockIdx.x * 64;
  int valid = Nn - n0;
  const float* xsrc = X + (size_t)n0 * 128;
  if (valid >= 64) {
    for (int i = threadIdx.x; i < 64 * 128; i += 256) xs[i] = xsrc[i];
  } else {
    for (int i = threadIdx.x; i < 64 * 128; i += 256)
      xs[i] = (i < valid * 128) ? xsrc[i] : 0.f;
  }
  __syncthreads();
  int cg = threadIdx.x & 15;
  int ng = threadIdx.x >> 4;
  int l  = threadIdx.x & 63;
  int cgc = cg < 10 ? cg : 9;
  float4 acc[4];
#pragma unroll
  for (int i = 0; i < 4; ++i) acc[i] = make_float4(0.f, 0.f, 0.f, 0.f);
  const float* wp = W + cgc * 4;
  for (int k = 0; k < 128; k += 4) {
    float4 w0 = *(const float4*)(wp + (k + 0) * 40);
    float4 w1 = *(const float4*)(wp + (k + 1) * 40);
    float4 w2 = *(const float4*)(wp + (k + 2) * 40);
    float4 w3 = *(const float4*)(wp + (k + 3) * 40);
#pragma unroll
    for (int i = 0; i < 4; ++i) {
      float4 xv = *(const float4*)&xs[(ng * 4 + i) * 128 + k];
      fma4(acc[i], xv.x, w0); fma4(acc[i], xv.y, w1);
      fma4(acc[i], xv.z, w2); fma4(acc[i], xv.w, w3);
    }
  }
  float4 as4 = make_float4(0.f, 0.f, 0.f, 0.f);
  float4 ad4 = make_float4(0.f, 0.f, 0.f, 0.f);
  if (cg < 10) {
    as4 = *(const float4*)&avs[cg * 4];   // avs2 is [1][40] flat
    ad4 = *(const float4*)&avd[cg * 4];
  }
#pragma unroll
  for (int i = 0; i < 4; ++i) {
    int n = n0 + ng * 4 + i;
    if (cg < 10 && n < Nn)
      *(float4*)&H32[(size_t)n * 40 + cg * 4] = acc[i];
    float s = acc[i].x * as4.x + acc[i].y * as4.y +
              acc[i].z * as4.z + acc[i].w * as4.w;   // 0 for cg>=10
    float d = acc[i].x * ad4.x + acc[i].y * ad4.y +
              acc[i].z * ad4.z + acc[i].w * ad4.w;
#pragma unroll
    for (int off = 8; off; off >>= 1) {     // uniform flow: full EXEC
      s += __shfl_xor(s, off);
      d += __shfl_xor(d, off);
    }
    if ((l & 15) == 0 && n < Nn) {
      asrc[n] = s;
      adst[n] = d;
    }
  }
}

// ======================= fused gather-aggregate ==========================

// layers 0/1: H=2,C=64, fp16 h. Lane owns channels {2*lane, 2*lane+1}.
// All __shfl calls in uniform control flow (EXEC lesson from round 3).
__global__ __launch_bounds__(256) void k_agg128(
    const int* __restrict__ rowptr, const int* __restrict__ srt,
    const __half* __restrict__ Hb, const float* __restrict__ asrc,
    const float* __restrict__ adst, const float* __restrict__ bias,
    float* __restrict__ out, int Nn)
{
  int wid = (blockIdx.x * 256 + threadIdx.x) >> 6;
  int lane = threadIdx.x & 63;
  if (wid >= Nn) return;
  int head = lane >> 5;
  float2 ad = *(const float2*)&adst[(size_t)wid * 2];
  float2 as = *(const float2*)&asrc[(size_t)wid * 2];
  float w0 = expf(lrelu(as.x + ad.x)), w1 = expf(lrelu(as.y + ad.y));
  float wSelf = head ? w1 : w0;
  float2 hv = __half22float2(
      *(const __half2*)(Hb + (size_t)wid * 128 + 2 * lane));
  float2 acc = make_float2(wSelf * hv.x, wSelf * hv.y);
  float den = wSelf;
  int beg = rowptr[wid], end = rowptr[wid + 1];
  for (int j0 = beg; j0 < end; j0 += 64) {
    int cnt = min(64, end - j0);
    int myS = 0;
    float2 myF = make_float2(0.f, 0.f);
    if (j0 + lane < end) {
      myS = srt[j0 + lane];
      float2 a = *(const float2*)&asrc[(size_t)myS * 2];
      myF.x = expf(lrelu(a.x + ad.x));
      myF.y = expf(lrelu(a.y + ad.y));
    }
    for (int k = 0; k < cnt; ++k) {
      int s = __shfl(myS, k);
      float fx = __shfl(myF.x, k);          // uniform flow: full EXEC
      float fy = __shfl(myF.y, k);
      float f = head ? fy : fx;
      float2 h = __half22float2(
          *(const __half2*)(Hb + (size_t)s * 128 + 2 * lane));
      acc.x = fmaf(f, h.x, acc.x);
      acc.y = fmaf(f, h.y, acc.y);
      den += f;
    }
  }
  float2 bv = *(const float2*)&bias[2 * lane];
  float v0 = acc.x / den + bv.x;
  float v1 = acc.y / den + bv.y;
  float2 o;
  o.x = v0 > 0.f ? v0 : expm1f(v0);
  o.y = v1 > 0.f ? v1 : expm1f(v1);
  *(float2*)&out[(size_t)wid * 128 + 2 * lane] = o;
}

// layer 2: H=1,C=40, fp32 h; epilogue = bias + row softmax -> final output.
__global__ __launch_bounds__(256) void k_agg40(
    const int* __restrict__ rowptr, const int* __restrict__ srt,
    const float* __restrict__ Hb, const float* __restrict__ asrc,
    const float* __restrict__ adst, const float* __restrict__ b2,
    float* __restrict__ out, int Nn)
{
  int wid = (blockIdx.x * 256 + threadIdx.x) >> 6;
  int lane = threadIdx.x & 63;
  if (wid >= Nn) return;
  float ad = adst[wid];
  float w = expf(lrelu(asrc[wid] + ad));
  float hv = (lane < 40) ? Hb[(size_t)wid * 40 + lane] : 0.f;
  float acc = w * hv;
  float den = w;
  int beg = rowptr[wid], end = rowptr[wid + 1];
  for (int j0 = beg; j0 < end; j0 += 64) {
    int cnt = min(64, end - j0);
    int myS = 0;
    float myF = 0.f;
    if (j0 + lane < end) {
      myS = srt[j0 + lane];
      myF = expf(lrelu(asrc[myS] + ad));
    }
    for (int k = 0; k < cnt; ++k) {
      int s = __shfl(myS, k);
      float f = __shfl(myF, k);
      float g = (lane < 40) ? Hb[(size_t)s * 40 + lane] : 0.f;
      acc = fmaf(f, g, acc);
      den += f;
    }
  }
  float v = (lane < 40) ? acc / den + b2[lane] : -3.4e38f;
  float m = v;
#pragma unroll
  for (int off = 32; off; off >>= 1) m = fmaxf(m, __shfl_xor(m, off));
  float ex = (lane < 40) ? expf(v - m) : 0.f;
  float ssum = ex;
#pragma unroll
  for (int off = 32; off; off >>= 1) ssum += __shfl_xor(ssum, off);
  if (lane < 40) out[(size_t)wid * 40 + lane] = ex / ssum;
}

// ======================= launch ==========================

extern "C" void kernel_launch(void* const* d_in, const int* in_sizes, int n_in,
                              void* d_out, int out_size, void* d_ws, size_t ws_size,
                              hipStream_t stream) {
  const float* x   = (const float*)d_in[0];
  const int*   ei  = (const int*)d_in[1];
  const float* W0  = (const float*)d_in[2];
  const float* as0 = (const float*)d_in[3];
  const float* ad0 = (const float*)d_in[4];
  const float* b0  = (const float*)d_in[5];
  const float* W1  = (const float*)d_in[6];
  const float* as1 = (const float*)d_in[7];
  const float* ad1 = (const float*)d_in[8];
  const float* b1  = (const float*)d_in[9];
  const float* W2  = (const float*)d_in[10];
  const float* as2 = (const float*)d_in[11];
  const float* ad2 = (const float*)d_in[12];
  const float* b2  = (const float*)d_in[13];
  float* out = (float*)d_out;

  const int N = in_sizes[0] / 128;
  const int E = in_sizes[1] / 2;

  // ws: obuf f32[N*128] | h16 half[N*128] | h32 f32[N*40] |
  //     asrc f32[N*2] | adst f32[N*2] |
  //     rowptr[pad(N+1)] | cursor[N] | srt[E] | bsums[1024]   (ints)
  char* wsb = (char*)d_ws;
  float*  obuf = (float*)wsb;
  __half* h16  = (__half*)(obuf + (size_t)N * 128);
  float*  h32  = (float*)(h16 + (size_t)N * 128);
  float*  asrc = h32 + (size_t)N * 40;
  float*  adst = asrc + (size_t)N * 2;
  int* rowptr  = (int*)(adst + (size_t)N * 2);
  int* cursor  = rowptr + ((N + 1 + 7) & ~7);
  int* srt     = cursor + N;
  int* bsums   = srt + E;

  dim3 blk(256);
  int g_lin  = (N + 63) / 64;
  int g_wave = (N + 3) / 4;                 // 1 wave per node
  int g_edge = (E + 255) / 256;
  int g_node = (N + 255) / 256;
  int nb     = (N + SCAN_BS - 1) / SCAN_BS; // scan1 blocks (<=1024)

  // ---- CSR build (edge list identical across layers) ----
  k_zero<<<g_node, blk, 0, stream>>>(cursor, N);
  k_hist<<<g_edge, blk, 0, stream>>>(ei, cursor, E);
  k_scan1<<<nb, blk, 0, stream>>>(cursor, rowptr, bsums, N);
  k_scan2<<<1, 1024, 0, stream>>>(bsums, rowptr + N, nb);
  k_scan3<<<g_node, blk, 0, stream>>>(bsums, rowptr, cursor, N);
  k_scatter<<<g_edge, blk, 0, stream>>>(ei, cursor, srt, E);

  // ---------------- layer 0 ----------------
  k_linear128f<<<g_lin, blk, 0, stream>>>(x, W0, as0, ad0, h16, asrc, adst, N);
  k_agg128<<<g_wave, blk, 0, stream>>>(rowptr, srt, h16, asrc, adst, b0, obuf, N);

  // ---------------- layer 1 ----------------
  k_linear128f<<<g_lin, blk, 0, stream>>>(obuf, W1, as1, ad1, h16, asrc, adst, N);
  k_agg128<<<g_wave, blk, 0, stream>>>(rowptr, srt, h16, asrc, adst, b1, obuf, N);

  // ---------------- layer 2 ----------------
  k_linear40f<<<g_lin, blk, 0, stream>>>(obuf, W2, as2, ad2, h32, asrc, adst, N);
  k_agg40<<<g_wave, blk, 0, stream>>>(rowptr, srt, h32, asrc, adst, b2, out, N);
}

// Round 10
// 657.662 us; speedup vs baseline: 3.8463x; 1.2225x over previous
//
#include <hip/hip_runtime.h>
#include <hip/hip_fp16.h>
#include <cstdint>

// GAT 3-layer forward for MI355X — round 10 (= round 9 resubmitted; GPU
// acquisition timed out before it ever ran).
// vs round 8 (804 us): CSR build rewritten as a block-level bucketed
// counting sort. Old build (zero+hist+scan123+scatter ~200us) suffered
// 16x write amplification (random 4B scatter -> 64B line dirties,
// WRITE_SIZE 106MB for a 6.4MB array) and 1.6M random device atomics.
// New build: LDS histograms + per-(block,bucket) range reservation ->
// contiguous run writes into a bucket-major buffer, then per-bucket
// fine sort in an L2-resident window. Identical rowptr/srt semantics;
// agg/linear kernels unchanged from round 8.

#define DEV __device__ __forceinline__
#define EPB 4096          // edges per block in bucket passes (256 thr x 16)
#define BSHIFT 7          // dsts per bucket = 128; NB = ceil(N/128) <= 1024

DEV float lrelu(float v) { return v > 0.f ? v : 0.2f * v; }

DEV void fma4(float4& a, float s, const float4& w) {
  a.x = fmaf(s, w.x, a.x); a.y = fmaf(s, w.y, a.y);
  a.z = fmaf(s, w.z, a.z); a.w = fmaf(s, w.w, a.w);
}

// ======================= bucketed CSR build ==========================

__global__ __launch_bounds__(1024) void k_zero(int* __restrict__ p, int n) {
  int i = blockIdx.x * 1024 + threadIdx.x;
  if (i < n) p[i] = 0;
}

// pass 1: global bucket counts via per-block LDS histogram
__global__ __launch_bounds__(256) void k_bhist(
    const int* __restrict__ ei, int* __restrict__ bucketCnt, int E, int NB)
{
  __shared__ int h[1024];
  int t = threadIdx.x;
  for (int i = t; i < 1024; i += 256) h[i] = 0;
  __syncthreads();
  int e0 = blockIdx.x * EPB;
  int e1 = min(E, e0 + EPB);
  for (int e = e0 + t; e < e1; e += 256)
    atomicAdd(&h[ei[E + e] >> BSHIFT], 1);
  __syncthreads();
  for (int b = t; b < NB; b += 256) {
    int c = h[b];
    if (c) atomicAdd(&bucketCnt[b], c);
  }
}

// pass 2: scan bucket counts -> bucketBase (exclusive), init bucketRes,
// write rowptr[N] = E.
__global__ __launch_bounds__(1024) void k_bscan(
    const int* __restrict__ bucketCnt, int* __restrict__ bucketBase,
    int* __restrict__ bucketRes, int* __restrict__ rowptrN, int NB)
{
  __shared__ int sm[1024];
  int t = threadIdx.x;
  sm[t] = (t < NB) ? bucketCnt[t] : 0;
  __syncthreads();
  for (int off = 1; off < 1024; off <<= 1) {
    int u = sm[t];
    int add = (t >= off) ? sm[t - off] : 0;
    __syncthreads();
    sm[t] = u + add;
    __syncthreads();
  }
  if (t < NB) {
    int excl = (t == 0) ? 0 : sm[t - 1];
    bucketBase[t] = excl;
    bucketRes[t]  = excl;
  }
  if (t == 0) {
    bucketBase[NB] = sm[1023];
    *rowptrN = sm[1023];
  }
}

// pass 3: coarse scatter into bucket-major buf, packed (src<<BSHIFT)|dstLocal.
// Each block reserves a contiguous range per bucket -> run-contiguous writes.
__global__ __launch_bounds__(256) void k_bucket(
    const int* __restrict__ ei, int* __restrict__ bucketRes,
    int* __restrict__ buf, int E, int NB)
{
  __shared__ int h[1024];
  __shared__ int cur[1024];
  int t = threadIdx.x;
  for (int i = t; i < 1024; i += 256) h[i] = 0;
  __syncthreads();
  int e0 = blockIdx.x * EPB;
  int e1 = min(E, e0 + EPB);
  for (int e = e0 + t; e < e1; e += 256)
    atomicAdd(&h[ei[E + e] >> BSHIFT], 1);
  __syncthreads();
  for (int b = t; b < NB; b += 256) {
    int c = h[b];
    if (c) cur[b] = atomicAdd(&bucketRes[b], c);
  }
  __syncthreads();
  for (int e = e0 + t; e < e1; e += 256) {
    int s = ei[e], d = ei[E + e];
    int b = d >> BSHIFT;
    int pos = atomicAdd(&cur[b], 1);
    buf[pos] = (s << BSHIFT) | (d & ((1 << BSHIFT) - 1));
  }
}

// pass 4: per-bucket fine counting sort -> rowptr + srt.
// One block per bucket; dst range = 128 nodes, writes land in an
// L2-resident window of ~8KB.
__global__ __launch_bounds__(256) void k_fine(
    const int* __restrict__ bucketBase, const int* __restrict__ buf,
    int* __restrict__ rowptr, int* __restrict__ srt, int Nn)
{
  __shared__ int sm[128];
  __shared__ int cur[128];
  int t = threadIdx.x;
  int nb = blockIdx.x;
  int beg = bucketBase[nb], endB = bucketBase[nb + 1];
  int d0 = nb << BSHIFT;
  if (t < 128) sm[t] = 0;
  __syncthreads();
  for (int e = beg + t; e < endB; e += 256)
    atomicAdd(&sm[buf[e] & 127], 1);
  __syncthreads();
  // inclusive scan of sm[0..127]
  for (int off = 1; off < 128; off <<= 1) {
    int u = 0, add = 0;
    if (t < 128) {
      u = sm[t];
      add = (t >= off) ? sm[t - off] : 0;
    }
    __syncthreads();
    if (t < 128) sm[t] = u + add;
    __syncthreads();
  }
  if (t < 128) {
    int excl = (t == 0) ? 0 : sm[t - 1];
    int d = d0 + t;
    if (d < Nn) rowptr[d] = beg + excl;
    cur[t] = beg + excl;
  }
  __syncthreads();
  for (int e = beg + t; e < endB; e += 256) {
    int v = buf[e];
    int pos = atomicAdd(&cur[v & 127], 1);
    srt[pos] = v >> BSHIFT;
  }
}

// ============ linear 128->128 with fused att-dots, fp16 h out ==============
__global__ __launch_bounds__(256) void k_linear128f(
    const float* __restrict__ X, const float* __restrict__ W,
    const float* __restrict__ avs, const float* __restrict__ avd,
    __half* __restrict__ H16, float* __restrict__ asrc,
    float* __restrict__ adst, int Nn)
{
  __shared__ float xs[64 * 128];
  int n0 = blockIdx.x * 64;
  int valid = Nn - n0;
  const float* xsrc = X + (size_t)n0 * 128;
  if (valid >= 64) {
    for (int i = threadIdx.x; i < 64 * 128; i += 256) xs[i] = xsrc[i];
  } else {
    for (int i = threadIdx.x; i < 64 * 128; i += 256)
      xs[i] = (i < valid * 128) ? xsrc[i] : 0.f;
  }
  __syncthreads();
  int cg = threadIdx.x & 31;
  int ng = threadIdx.x >> 5;
  int l  = threadIdx.x & 63;
  float4 acc[8];
#pragma unroll
  for (int i = 0; i < 8; ++i) acc[i] = make_float4(0.f, 0.f, 0.f, 0.f);
  const float* wp = W + cg * 4;
  for (int k = 0; k < 128; k += 4) {
    float4 w0 = *(const float4*)(wp + (k + 0) * 128);
    float4 w1 = *(const float4*)(wp + (k + 1) * 128);
    float4 w2 = *(const float4*)(wp + (k + 2) * 128);
    float4 w3 = *(const float4*)(wp + (k + 3) * 128);
#pragma unroll
    for (int i = 0; i < 8; ++i) {
      float4 xv = *(const float4*)&xs[(ng * 8 + i) * 128 + k];
      fma4(acc[i], xv.x, w0); fma4(acc[i], xv.y, w1);
      fma4(acc[i], xv.z, w2); fma4(acc[i], xv.w, w3);
    }
  }
  float4 as4 = *(const float4*)&avs[cg * 4];   // avs is [2][64] flat = 128
  float4 ad4 = *(const float4*)&avd[cg * 4];
#pragma unroll
  for (int i = 0; i < 8; ++i) {
    int n = n0 + ng * 8 + i;
    if (n < Nn) {
      __half2 p0 = __floats2half2_rn(acc[i].x, acc[i].y);
      __half2 p1 = __floats2half2_rn(acc[i].z, acc[i].w);
      __half2* dst = (__half2*)(H16 + (size_t)n * 128 + cg * 4);
      dst[0] = p0; dst[1] = p1;
    }
    float s = acc[i].x * as4.x + acc[i].y * as4.y +
              acc[i].z * as4.z + acc[i].w * as4.w;
    float d = acc[i].x * ad4.x + acc[i].y * ad4.y +
              acc[i].z * ad4.z + acc[i].w * ad4.w;
#pragma unroll
    for (int off = 8; off; off >>= 1) {     // uniform flow: full EXEC
      s += __shfl_xor(s, off);
      d += __shfl_xor(d, off);
    }
    if ((l & 15) == 0 && n < Nn) {
      int head = (l >> 4) & 1;
      asrc[(size_t)n * 2 + head] = s;
      adst[(size_t)n * 2 + head] = d;
    }
  }
}

// ============ linear 128->40 with fused att-dots, fp32 h out ===============
__global__ __launch_bounds__(256) void k_linear40f(
    const float* __restrict__ X, const float* __restrict__ W,
    const float* __restrict__ avs, const float* __restrict__ avd,
    float* __restrict__ H32, float* __restrict__ asrc,
    float* __restrict__ adst, int Nn)
{
  __shared__ float xs[64 * 128];
  int n0 = blockIdx.x * 64;
  int valid = Nn - n0;
  const float* xsrc = X + (size_t)n0 * 128;
  if (valid >= 64) {
    for (int i = threadIdx.x; i < 64 * 128; i += 256) xs[i] = xsrc[i];
  } else {
    for (int i = threadIdx.x; i < 64 * 128; i += 256)
      xs[i] = (i < valid * 128) ? xsrc[i] : 0.f;
  }
  __syncthreads();
  int cg = threadIdx.x & 15;
  int ng = threadIdx.x >> 4;
  int l  = threadIdx.x & 63;
  int cgc = cg < 10 ? cg : 9;
  float4 acc[4];
#pragma unroll
  for (int i = 0; i < 4; ++i) acc[i] = make_float4(0.f, 0.f, 0.f, 0.f);
  const float* wp = W + cgc * 4;
  for (int k = 0; k < 128; k += 4) {
    float4 w0 = *(const float4*)(wp + (k + 0) * 40);
    float4 w1 = *(const float4*)(wp + (k + 1) * 40);
    float4 w2 = *(const float4*)(wp + (k + 2) * 40);
    float4 w3 = *(const float4*)(wp + (k + 3) * 40);
#pragma unroll
    for (int i = 0; i < 4; ++i) {
      float4 xv = *(const float4*)&xs[(ng * 4 + i) * 128 + k];
      fma4(acc[i], xv.x, w0); fma4(acc[i], xv.y, w1);
      fma4(acc[i], xv.z, w2); fma4(acc[i], xv.w, w3);
    }
  }
  float4 as4 = make_float4(0.f, 0.f, 0.f, 0.f);
  float4 ad4 = make_float4(0.f, 0.f, 0.f, 0.f);
  if (cg < 10) {
    as4 = *(const float4*)&avs[cg * 4];
    ad4 = *(const float4*)&avd[cg * 4];
  }
#pragma unroll
  for (int i = 0; i < 4; ++i) {
    int n = n0 + ng * 4 + i;
    if (cg < 10 && n < Nn)
      *(float4*)&H32[(size_t)n * 40 + cg * 4] = acc[i];
    float s = acc[i].x * as4.x + acc[i].y * as4.y +
              acc[i].z * as4.z + acc[i].w * as4.w;   // 0 for cg>=10
    float d = acc[i].x * ad4.x + acc[i].y * ad4.y +
              acc[i].z * ad4.z + acc[i].w * ad4.w;
#pragma unroll
    for (int off = 8; off; off >>= 1) {     // uniform flow: full EXEC
      s += __shfl_xor(s, off);
      d += __shfl_xor(d, off);
    }
    if ((l & 15) == 0 && n < Nn) {
      asrc[n] = s;
      adst[n] = d;
    }
  }
}

// ======================= fused gather-aggregate ==========================

// layers 0/1: H=2,C=64, fp16 h. Lane owns channels {2*lane, 2*lane+1}.
// All __shfl calls in uniform control flow (EXEC lesson from round 3).
__global__ __launch_bounds__(256) void k_agg128(
    const int* __restrict__ rowptr, const int* __restrict__ srt,
    const __half* __restrict__ Hb, const float* __restrict__ asrc,
    const float* __restrict__ adst, const float* __restrict__ bias,
    float* __restrict__ out, int Nn)
{
  int wid = (blockIdx.x * 256 + threadIdx.x) >> 6;
  int lane = threadIdx.x & 63;
  if (wid >= Nn) return;
  int head = lane >> 5;
  float2 ad = *(const float2*)&adst[(size_t)wid * 2];
  float2 as = *(const float2*)&asrc[(size_t)wid * 2];
  float w0 = expf(lrelu(as.x + ad.x)), w1 = expf(lrelu(as.y + ad.y));
  float wSelf = head ? w1 : w0;
  float2 hv = __half22float2(
      *(const __half2*)(Hb + (size_t)wid * 128 + 2 * lane));
  float2 acc = make_float2(wSelf * hv.x, wSelf * hv.y);
  float den = wSelf;
  int beg = rowptr[wid], end = rowptr[wid + 1];
  for (int j0 = beg; j0 < end; j0 += 64) {
    int cnt = min(64, end - j0);
    int myS = 0;
    float2 myF = make_float2(0.f, 0.f);
    if (j0 + lane < end) {
      myS = srt[j0 + lane];
      float2 a = *(const float2*)&asrc[(size_t)myS * 2];
      myF.x = expf(lrelu(a.x + ad.x));
      myF.y = expf(lrelu(a.y + ad.y));
    }
    for (int k = 0; k < cnt; ++k) {
      int s = __shfl(myS, k);
      float fx = __shfl(myF.x, k);          // uniform flow: full EXEC
      float fy = __shfl(myF.y, k);
      float f = head ? fy : fx;
      float2 h = __half22float2(
          *(const __half2*)(Hb + (size_t)s * 128 + 2 * lane));
      acc.x = fmaf(f, h.x, acc.x);
      acc.y = fmaf(f, h.y, acc.y);
      den += f;
    }
  }
  float2 bv = *(const float2*)&bias[2 * lane];
  float v0 = acc.x / den + bv.x;
  float v1 = acc.y / den + bv.y;
  float2 o;
  o.x = v0 > 0.f ? v0 : expm1f(v0);
  o.y = v1 > 0.f ? v1 : expm1f(v1);
  *(float2*)&out[(size_t)wid * 128 + 2 * lane] = o;
}

// layer 2: H=1,C=40, fp32 h; epilogue = bias + row softmax -> final output.
__global__ __launch_bounds__(256) void k_agg40(
    const int* __restrict__ rowptr, const int* __restrict__ srt,
    const float* __restrict__ Hb, const float* __restrict__ asrc,
    const float* __restrict__ adst, const float* __restrict__ b2,
    float* __restrict__ out, int Nn)
{
  int wid = (blockIdx.x * 256 + threadIdx.x) >> 6;
  int lane = threadIdx.x & 63;
  if (wid >= Nn) return;
  float ad = adst[wid];
  float w = expf(lrelu(asrc[wid] + ad));
  float hv = (lane < 40) ? Hb[(size_t)wid * 40 + lane] : 0.f;
  float acc = w * hv;
  float den = w;
  int beg = rowptr[wid], end = rowptr[wid + 1];
  for (int j0 = beg; j0 < end; j0 += 64) {
    int cnt = min(64, end - j0);
    int myS = 0;
    float myF = 0.f;
    if (j0 + lane < end) {
      myS = srt[j0 + lane];
      myF = expf(lrelu(asrc[myS] + ad));
    }
    for (int k = 0; k < cnt; ++k) {
      int s = __shfl(myS, k);
      float f = __shfl(myF, k);
      float g = (lane < 40) ? Hb[(size_t)s * 40 + lane] : 0.f;
      acc = fmaf(f, g, acc);
      den += f;
    }
  }
  float v = (lane < 40) ? acc / den + b2[lane] : -3.4e38f;
  float m = v;
#pragma unroll
  for (int off = 32; off; off >>= 1) m = fmaxf(m, __shfl_xor(m, off));
  float ex = (lane < 40) ? expf(v - m) : 0.f;
  float ssum = ex;
#pragma unroll
  for (int off = 32; off; off >>= 1) ssum += __shfl_xor(ssum, off);
  if (lane < 40) out[(size_t)wid * 40 + lane] = ex / ssum;
}

// ======================= launch ==========================

extern "C" void kernel_launch(void* const* d_in, const int* in_sizes, int n_in,
                              void* d_out, int out_size, void* d_ws, size_t ws_size,
                              hipStream_t stream) {
  const float* x   = (const float*)d_in[0];
  const int*   ei  = (const int*)d_in[1];
  const float* W0  = (const float*)d_in[2];
  const float* as0 = (const float*)d_in[3];
  const float* ad0 = (const float*)d_in[4];
  const float* b0  = (const float*)d_in[5];
  const float* W1  = (const float*)d_in[6];
  const float* as1 = (const float*)d_in[7];
  const float* ad1 = (const float*)d_in[8];
  const float* b1  = (const float*)d_in[9];
  const float* W2  = (const float*)d_in[10];
  const float* as2 = (const float*)d_in[11];
  const float* ad2 = (const float*)d_in[12];
  const float* b2  = (const float*)d_in[13];
  float* out = (float*)d_out;

  const int N = in_sizes[0] / 128;
  const int E = in_sizes[1] / 2;
  const int NB = ((N - 1) >> BSHIFT) + 1;   // 782 for N=100000 (<=1024)

  // ws: obuf f32[N*128] | h16 half[N*128] | h32 f32[N*40] |
  //     asrc f32[N*2] | adst f32[N*2] |
  //     rowptr[pad(N+1)] | srt[E] | buf[E] |
  //     bucketCnt[1024] | bucketBase[1025] | bucketRes[1024]   (ints)
  char* wsb = (char*)d_ws;
  float*  obuf = (float*)wsb;
  __half* h16  = (__half*)(obuf + (size_t)N * 128);
  float*  h32  = (float*)(h16 + (size_t)N * 128);
  float*  asrc = h32 + (size_t)N * 40;
  float*  adst = asrc + (size_t)N * 2;
  int* rowptr  = (int*)(adst + (size_t)N * 2);
  int* srt     = rowptr + ((N + 1 + 7) & ~7);
  int* buf     = srt + E;
  int* bucketCnt  = buf + E;
  int* bucketBase = bucketCnt + 1024;
  int* bucketRes  = bucketBase + 1025;

  dim3 blk(256);
  int g_lin  = (N + 63) / 64;
  int g_wave = (N + 3) / 4;                 // 1 wave per node
  int g_bkt  = (E + EPB - 1) / EPB;         // 391 for E=1.6M

  // ---- bucketed CSR build (edge list identical across layers) ----
  k_zero<<<1, 1024, 0, stream>>>(bucketCnt, NB);
  k_bhist<<<g_bkt, blk, 0, stream>>>(ei, bucketCnt, E, NB);
  k_bscan<<<1, 1024, 0, stream>>>(bucketCnt, bucketBase, bucketRes,
                                  rowptr + N, NB);
  k_bucket<<<g_bkt, blk, 0, stream>>>(ei, bucketRes, buf, E, NB);
  k_fine<<<NB, blk, 0, stream>>>(bucketBase, buf, rowptr, srt, N);

  // ---------------- layer 0 ----------------
  k_linear128f<<<g_lin, blk, 0, stream>>>(x, W0, as0, ad0, h16, asrc, adst, N);
  k_agg128<<<g_wave, blk, 0, stream>>>(rowptr, srt, h16, asrc, adst, b0, obuf, N);

  // ---------------- layer 1 ----------------
  k_linear128f<<<g_lin, blk, 0, stream>>>(obuf, W1, as1, ad1, h16, asrc, adst, N);
  k_agg128<<<g_wave, blk, 0, stream>>>(rowptr, srt, h16, asrc, adst, b1, obuf, N);

  // ---------------- layer 2 ----------------
  k_linear40f<<<g_lin, blk, 0, stream>>>(obuf, W2, as2, ad2, h32, asrc, adst, N);
  k_agg40<<<g_wave, blk, 0, stream>>>(rowptr, srt, h32, asrc, adst, b2, out, N);
}

// Round 11
// 531.409 us; speedup vs baseline: 4.7601x; 1.2376x over previous
//
#include <hip/hip_runtime.h>
#include <hip/hip_fp16.h>
#include <cstdint>

// GAT 3-layer forward for MI355X — round 11.
// vs round 10 (658 us):
//  * agg inner loops 4x-unrolled: 4 independent h-row gathers in flight per
//    wave (round-10 counters showed agg is latency-bound, not bytes-bound:
//    dur fell only 13% when FETCH halved; 2.19 TB/s vs 3.55 sustained).
//    All shuffles remain in wave-uniform control flow (EXEC lesson, round 3).
//  * layer-2 h stored fp16 (k_linear40f epilogue) -> k_agg40 gathers 80 B/edge
//    instead of 160. Sole numerics change this round.

#define DEV __device__ __forceinline__
#define EPB 4096          // edges per block in bucket passes (256 thr x 16)
#define BSHIFT 7          // dsts per bucket = 128; NB = ceil(N/128) <= 1024

DEV float lrelu(float v) { return v > 0.f ? v : 0.2f * v; }

DEV void fma4(float4& a, float s, const float4& w) {
  a.x = fmaf(s, w.x, a.x); a.y = fmaf(s, w.y, a.y);
  a.z = fmaf(s, w.z, a.z); a.w = fmaf(s, w.w, a.w);
}

// ======================= bucketed CSR build ==========================

__global__ __launch_bounds__(1024) void k_zero(int* __restrict__ p, int n) {
  int i = blockIdx.x * 1024 + threadIdx.x;
  if (i < n) p[i] = 0;
}

__global__ __launch_bounds__(256) void k_bhist(
    const int* __restrict__ ei, int* __restrict__ bucketCnt, int E, int NB)
{
  __shared__ int h[1024];
  int t = threadIdx.x;
  for (int i = t; i < 1024; i += 256) h[i] = 0;
  __syncthreads();
  int e0 = blockIdx.x * EPB;
  int e1 = min(E, e0 + EPB);
  for (int e = e0 + t; e < e1; e += 256)
    atomicAdd(&h[ei[E + e] >> BSHIFT], 1);
  __syncthreads();
  for (int b = t; b < NB; b += 256) {
    int c = h[b];
    if (c) atomicAdd(&bucketCnt[b], c);
  }
}

__global__ __launch_bounds__(1024) void k_bscan(
    const int* __restrict__ bucketCnt, int* __restrict__ bucketBase,
    int* __restrict__ bucketRes, int* __restrict__ rowptrN, int NB)
{
  __shared__ int sm[1024];
  int t = threadIdx.x;
  sm[t] = (t < NB) ? bucketCnt[t] : 0;
  __syncthreads();
  for (int off = 1; off < 1024; off <<= 1) {
    int u = sm[t];
    int add = (t >= off) ? sm[t - off] : 0;
    __syncthreads();
    sm[t] = u + add;
    __syncthreads();
  }
  if (t < NB) {
    int excl = (t == 0) ? 0 : sm[t - 1];
    bucketBase[t] = excl;
    bucketRes[t]  = excl;
  }
  if (t == 0) {
    bucketBase[NB] = sm[1023];
    *rowptrN = sm[1023];
  }
}

__global__ __launch_bounds__(256) void k_bucket(
    const int* __restrict__ ei, int* __restrict__ bucketRes,
    int* __restrict__ buf, int E, int NB)
{
  __shared__ int h[1024];
  __shared__ int cur[1024];
  int t = threadIdx.x;
  for (int i = t; i < 1024; i += 256) h[i] = 0;
  __syncthreads();
  int e0 = blockIdx.x * EPB;
  int e1 = min(E, e0 + EPB);
  for (int e = e0 + t; e < e1; e += 256)
    atomicAdd(&h[ei[E + e] >> BSHIFT], 1);
  __syncthreads();
  for (int b = t; b < NB; b += 256) {
    int c = h[b];
    if (c) cur[b] = atomicAdd(&bucketRes[b], c);
  }
  __syncthreads();
  for (int e = e0 + t; e < e1; e += 256) {
    int s = ei[e], d = ei[E + e];
    int b = d >> BSHIFT;
    int pos = atomicAdd(&cur[b], 1);
    buf[pos] = (s << BSHIFT) | (d & ((1 << BSHIFT) - 1));
  }
}

__global__ __launch_bounds__(256) void k_fine(
    const int* __restrict__ bucketBase, const int* __restrict__ buf,
    int* __restrict__ rowptr, int* __restrict__ srt, int Nn)
{
  __shared__ int sm[128];
  __shared__ int cur[128];
  int t = threadIdx.x;
  int nb = blockIdx.x;
  int beg = bucketBase[nb], endB = bucketBase[nb + 1];
  int d0 = nb << BSHIFT;
  if (t < 128) sm[t] = 0;
  __syncthreads();
  for (int e = beg + t; e < endB; e += 256)
    atomicAdd(&sm[buf[e] & 127], 1);
  __syncthreads();
  for (int off = 1; off < 128; off <<= 1) {
    int u = 0, add = 0;
    if (t < 128) {
      u = sm[t];
      add = (t >= off) ? sm[t - off] : 0;
    }
    __syncthreads();
    if (t < 128) sm[t] = u + add;
    __syncthreads();
  }
  if (t < 128) {
    int excl = (t == 0) ? 0 : sm[t - 1];
    int d = d0 + t;
    if (d < Nn) rowptr[d] = beg + excl;
    cur[t] = beg + excl;
  }
  __syncthreads();
  for (int e = beg + t; e < endB; e += 256) {
    int v = buf[e];
    int pos = atomicAdd(&cur[v & 127], 1);
    srt[pos] = v >> BSHIFT;
  }
}

// ============ linear 128->128 with fused att-dots, fp16 h out ==============
__global__ __launch_bounds__(256) void k_linear128f(
    const float* __restrict__ X, const float* __restrict__ W,
    const float* __restrict__ avs, const float* __restrict__ avd,
    __half* __restrict__ H16, float* __restrict__ asrc,
    float* __restrict__ adst, int Nn)
{
  __shared__ float xs[64 * 128];
  int n0 = blockIdx.x * 64;
  int valid = Nn - n0;
  const float* xsrc = X + (size_t)n0 * 128;
  if (valid >= 64) {
    for (int i = threadIdx.x; i < 64 * 128; i += 256) xs[i] = xsrc[i];
  } else {
    for (int i = threadIdx.x; i < 64 * 128; i += 256)
      xs[i] = (i < valid * 128) ? xsrc[i] : 0.f;
  }
  __syncthreads();
  int cg = threadIdx.x & 31;
  int ng = threadIdx.x >> 5;
  int l  = threadIdx.x & 63;
  float4 acc[8];
#pragma unroll
  for (int i = 0; i < 8; ++i) acc[i] = make_float4(0.f, 0.f, 0.f, 0.f);
  const float* wp = W + cg * 4;
  for (int k = 0; k < 128; k += 4) {
    float4 w0 = *(const float4*)(wp + (k + 0) * 128);
    float4 w1 = *(const float4*)(wp + (k + 1) * 128);
    float4 w2 = *(const float4*)(wp + (k + 2) * 128);
    float4 w3 = *(const float4*)(wp + (k + 3) * 128);
#pragma unroll
    for (int i = 0; i < 8; ++i) {
      float4 xv = *(const float4*)&xs[(ng * 8 + i) * 128 + k];
      fma4(acc[i], xv.x, w0); fma4(acc[i], xv.y, w1);
      fma4(acc[i], xv.z, w2); fma4(acc[i], xv.w, w3);
    }
  }
  float4 as4 = *(const float4*)&avs[cg * 4];   // avs is [2][64] flat = 128
  float4 ad4 = *(const float4*)&avd[cg * 4];
#pragma unroll
  for (int i = 0; i < 8; ++i) {
    int n = n0 + ng * 8 + i;
    if (n < Nn) {
      __half2 p0 = __floats2half2_rn(acc[i].x, acc[i].y);
      __half2 p1 = __floats2half2_rn(acc[i].z, acc[i].w);
      __half2* dst = (__half2*)(H16 + (size_t)n * 128 + cg * 4);
      dst[0] = p0; dst[1] = p1;
    }
    float s = acc[i].x * as4.x + acc[i].y * as4.y +
              acc[i].z * as4.z + acc[i].w * as4.w;
    float d = acc[i].x * ad4.x + acc[i].y * ad4.y +
              acc[i].z * ad4.z + acc[i].w * ad4.w;
#pragma unroll
    for (int off = 8; off; off >>= 1) {     // uniform flow: full EXEC
      s += __shfl_xor(s, off);
      d += __shfl_xor(d, off);
    }
    if ((l & 15) == 0 && n < Nn) {
      int head = (l >> 4) & 1;
      asrc[(size_t)n * 2 + head] = s;
      adst[(size_t)n * 2 + head] = d;
    }
  }
}

// ============ linear 128->40 with fused att-dots, fp16 h out ===============
__global__ __launch_bounds__(256) void k_linear40f(
    const float* __restrict__ X, const float* __restrict__ W,
    const float* __restrict__ avs, const float* __restrict__ avd,
    __half* __restrict__ H16b, float* __restrict__ asrc,
    float* __restrict__ adst, int Nn)
{
  __shared__ float xs[64 * 128];
  int n0 = blockIdx.x * 64;
  int valid = Nn - n0;
  const float* xsrc = X + (size_t)n0 * 128;
  if (valid >= 64) {
    for (int i = threadIdx.x; i < 64 * 128; i += 256) xs[i] = xsrc[i];
  } else {
    for (int i = threadIdx.x; i < 64 * 128; i += 256)
      xs[i] = (i < valid * 128) ? xsrc[i] : 0.f;
  }
  __syncthreads();
  int cg = threadIdx.x & 15;
  int ng = threadIdx.x >> 4;
  int l  = threadIdx.x & 63;
  int cgc = cg < 10 ? cg : 9;
  float4 acc[4];
#pragma unroll
  for (int i = 0; i < 4; ++i) acc[i] = make_float4(0.f, 0.f, 0.f, 0.f);
  const float* wp = W + cgc * 4;
  for (int k = 0; k < 128; k += 4) {
    float4 w0 = *(const float4*)(wp + (k + 0) * 40);
    float4 w1 = *(const float4*)(wp + (k + 1) * 40);
    float4 w2 = *(const float4*)(wp + (k + 2) * 40);
    float4 w3 = *(const float4*)(wp + (k + 3) * 40);
#pragma unroll
    for (int i = 0; i < 4; ++i) {
      float4 xv = *(const float4*)&xs[(ng * 4 + i) * 128 + k];
      fma4(acc[i], xv.x, w0); fma4(acc[i], xv.y, w1);
      fma4(acc[i], xv.z, w2); fma4(acc[i], xv.w, w3);
    }
  }
  float4 as4 = make_float4(0.f, 0.f, 0.f, 0.f);
  float4 ad4 = make_float4(0.f, 0.f, 0.f, 0.f);
  if (cg < 10) {
    as4 = *(const float4*)&avs[cg * 4];
    ad4 = *(const float4*)&avd[cg * 4];
  }
#pragma unroll
  for (int i = 0; i < 4; ++i) {
    int n = n0 + ng * 4 + i;
    if (cg < 10 && n < Nn) {
      __half2 q0 = __floats2half2_rn(acc[i].x, acc[i].y);
      __half2 q1 = __floats2half2_rn(acc[i].z, acc[i].w);
      __half2* dst = (__half2*)(H16b + (size_t)n * 40 + cg * 4);
      dst[0] = q0; dst[1] = q1;
    }
    float s = acc[i].x * as4.x + acc[i].y * as4.y +
              acc[i].z * as4.z + acc[i].w * as4.w;   // 0 for cg>=10
    float d = acc[i].x * ad4.x + acc[i].y * ad4.y +
              acc[i].z * ad4.z + acc[i].w * ad4.w;
#pragma unroll
    for (int off = 8; off; off >>= 1) {     // uniform flow: full EXEC
      s += __shfl_xor(s, off);
      d += __shfl_xor(d, off);
    }
    if ((l & 15) == 0 && n < Nn) {
      asrc[n] = s;
      adst[n] = d;
    }
  }
}

// ======================= fused gather-aggregate ==========================

// layers 0/1: H=2,C=64, fp16 h. Lane owns channels {2*lane, 2*lane+1}.
// Inner loop 4x-unrolled: 4 independent row gathers in flight.
// All __shfl in wave-uniform control flow (beg/end/cnt uniform per wave).
__global__ __launch_bounds__(256) void k_agg128(
    const int* __restrict__ rowptr, const int* __restrict__ srt,
    const __half* __restrict__ Hb, const float* __restrict__ asrc,
    const float* __restrict__ adst, const float* __restrict__ bias,
    float* __restrict__ out, int Nn)
{
  int wid = (blockIdx.x * 256 + threadIdx.x) >> 6;
  int lane = threadIdx.x & 63;
  if (wid >= Nn) return;
  int head = lane >> 5;
  const __half2* Hb2 = (const __half2*)Hb;      // row stride 64 half2
  float2 ad = *(const float2*)&adst[(size_t)wid * 2];
  float2 as = *(const float2*)&asrc[(size_t)wid * 2];
  float w0 = expf(lrelu(as.x + ad.x)), w1 = expf(lrelu(as.y + ad.y));
  float wSelf = head ? w1 : w0;
  float2 hv = __half22float2(Hb2[(size_t)wid * 64 + lane]);
  float accx = wSelf * hv.x, accy = wSelf * hv.y;
  float den = wSelf;
  int beg = rowptr[wid], end = rowptr[wid + 1];
  for (int j0 = beg; j0 < end; j0 += 64) {
    int cnt = min(64, end - j0);
    int myS = 0;
    float2 myF = make_float2(0.f, 0.f);
    if (j0 + lane < end) {
      myS = srt[j0 + lane];
      float2 a = *(const float2*)&asrc[(size_t)myS * 2];
      myF.x = expf(lrelu(a.x + ad.x));
      myF.y = expf(lrelu(a.y + ad.y));
    }
    int k = 0;
    for (; k + 4 <= cnt; k += 4) {
      int s0 = __shfl(myS, k + 0), s1 = __shfl(myS, k + 1);
      int s2 = __shfl(myS, k + 2), s3 = __shfl(myS, k + 3);
      float fx0 = __shfl(myF.x, k + 0), fy0 = __shfl(myF.y, k + 0);
      float fx1 = __shfl(myF.x, k + 1), fy1 = __shfl(myF.y, k + 1);
      float fx2 = __shfl(myF.x, k + 2), fy2 = __shfl(myF.y, k + 2);
      float fx3 = __shfl(myF.x, k + 3), fy3 = __shfl(myF.y, k + 3);
      __half2 h0 = Hb2[(size_t)s0 * 64 + lane];
      __half2 h1 = Hb2[(size_t)s1 * 64 + lane];
      __half2 h2 = Hb2[(size_t)s2 * 64 + lane];
      __half2 h3 = Hb2[(size_t)s3 * 64 + lane];
      float f0 = head ? fy0 : fx0;
      float f1 = head ? fy1 : fx1;
      float f2 = head ? fy2 : fx2;
      float f3 = head ? fy3 : fx3;
      float2 g0 = __half22float2(h0), g1 = __half22float2(h1);
      float2 g2 = __half22float2(h2), g3 = __half22float2(h3);
      accx = fmaf(f0, g0.x, accx); accy = fmaf(f0, g0.y, accy);
      accx = fmaf(f1, g1.x, accx); accy = fmaf(f1, g1.y, accy);
      accx = fmaf(f2, g2.x, accx); accy = fmaf(f2, g2.y, accy);
      accx = fmaf(f3, g3.x, accx); accy = fmaf(f3, g3.y, accy);
      den += f0 + f1 + f2 + f3;
    }
    for (; k < cnt; ++k) {
      int s = __shfl(myS, k);
      float fx = __shfl(myF.x, k), fy = __shfl(myF.y, k);
      float f = head ? fy : fx;
      float2 g = __half22float2(Hb2[(size_t)s * 64 + lane]);
      accx = fmaf(f, g.x, accx);
      accy = fmaf(f, g.y, accy);
      den += f;
    }
  }
  float2 bv = *(const float2*)&bias[2 * lane];
  float v0 = accx / den + bv.x;
  float v1 = accy / den + bv.y;
  float2 o;
  o.x = v0 > 0.f ? v0 : expm1f(v0);
  o.y = v1 > 0.f ? v1 : expm1f(v1);
  *(float2*)&out[(size_t)wid * 128 + 2 * lane] = o;
}

// layer 2: H=1,C=40, fp16 h. Lanes 0..19 own channel pairs {2l, 2l+1}.
// Epilogue = bias + row softmax (64-lane reduce with neutral values).
__global__ __launch_bounds__(256) void k_agg40(
    const int* __restrict__ rowptr, const int* __restrict__ srt,
    const __half* __restrict__ Hb, const float* __restrict__ asrc,
    const float* __restrict__ adst, const float* __restrict__ b2,
    float* __restrict__ out, int Nn)
{
  int wid = (blockIdx.x * 256 + threadIdx.x) >> 6;
  int lane = threadIdx.x & 63;
  if (wid >= Nn) return;
  const __half2* Hb2 = (const __half2*)Hb;      // row stride 20 half2
  int li = min(lane, 19);                       // clamped (in-bounds loads)
  bool act = lane < 20;
  float ad = adst[wid];
  float w = expf(lrelu(asrc[wid] + ad));
  float2 hv = __half22float2(Hb2[(size_t)wid * 20 + li]);
  float accx = w * hv.x, accy = w * hv.y;       // garbage in lanes>=20, masked later
  float den = w;
  int beg = rowptr[wid], end = rowptr[wid + 1];
  for (int j0 = beg; j0 < end; j0 += 64) {
    int cnt = min(64, end - j0);
    int myS = 0;
    float myF = 0.f;
    if (j0 + lane < end) {
      myS = srt[j0 + lane];
      myF = expf(lrelu(asrc[myS] + ad));
    }
    int k = 0;
    for (; k + 4 <= cnt; k += 4) {
      int s0 = __shfl(myS, k + 0), s1 = __shfl(myS, k + 1);
      int s2 = __shfl(myS, k + 2), s3 = __shfl(myS, k + 3);
      float f0 = __shfl(myF, k + 0), f1 = __shfl(myF, k + 1);
      float f2 = __shfl(myF, k + 2), f3 = __shfl(myF, k + 3);
      __half2 h0 = Hb2[(size_t)s0 * 20 + li];
      __half2 h1 = Hb2[(size_t)s1 * 20 + li];
      __half2 h2 = Hb2[(size_t)s2 * 20 + li];
      __half2 h3 = Hb2[(size_t)s3 * 20 + li];
      float2 g0 = __half22float2(h0), g1 = __half22float2(h1);
      float2 g2 = __half22float2(h2), g3 = __half22float2(h3);
      accx = fmaf(f0, g0.x, accx); accy = fmaf(f0, g0.y, accy);
      accx = fmaf(f1, g1.x, accx); accy = fmaf(f1, g1.y, accy);
      accx = fmaf(f2, g2.x, accx); accy = fmaf(f2, g2.y, accy);
      accx = fmaf(f3, g3.x, accx); accy = fmaf(f3, g3.y, accy);
      den += f0 + f1 + f2 + f3;
    }
    for (; k < cnt; ++k) {
      int s = __shfl(myS, k);
      float f = __shfl(myF, k);
      float2 g = __half22float2(Hb2[(size_t)s * 20 + li]);
      accx = fmaf(f, g.x, accx);
      accy = fmaf(f, g.y, accy);
      den += f;
    }
  }
  float2 bv = *(const float2*)&b2[2 * li];
  float v0 = act ? accx / den + bv.x : -3.4e38f;
  float v1 = act ? accy / den + bv.y : -3.4e38f;
  float m = fmaxf(v0, v1);
#pragma unroll
  for (int off = 32; off; off >>= 1) m = fmaxf(m, __shfl_xor(m, off));
  float e0 = act ? expf(v0 - m) : 0.f;
  float e1 = act ? expf(v1 - m) : 0.f;
  float ss = e0 + e1;
#pragma unroll
  for (int off = 32; off; off >>= 1) ss += __shfl_xor(ss, off);
  if (act)
    *(float2*)&out[(size_t)wid * 40 + 2 * li] = make_float2(e0 / ss, e1 / ss);
}

// ======================= launch ==========================

extern "C" void kernel_launch(void* const* d_in, const int* in_sizes, int n_in,
                              void* d_out, int out_size, void* d_ws, size_t ws_size,
                              hipStream_t stream) {
  const float* x   = (const float*)d_in[0];
  const int*   ei  = (const int*)d_in[1];
  const float* W0  = (const float*)d_in[2];
  const float* as0 = (const float*)d_in[3];
  const float* ad0 = (const float*)d_in[4];
  const float* b0  = (const float*)d_in[5];
  const float* W1  = (const float*)d_in[6];
  const float* as1 = (const float*)d_in[7];
  const float* ad1 = (const float*)d_in[8];
  const float* b1  = (const float*)d_in[9];
  const float* W2  = (const float*)d_in[10];
  const float* as2 = (const float*)d_in[11];
  const float* ad2 = (const float*)d_in[12];
  const float* b2  = (const float*)d_in[13];
  float* out = (float*)d_out;

  const int N = in_sizes[0] / 128;
  const int E = in_sizes[1] / 2;
  const int NB = ((N - 1) >> BSHIFT) + 1;   // 782 for N=100000 (<=1024)

  // ws: obuf f32[N*128] | h16 half[N*128] | h16b half[N*40] |
  //     asrc f32[N*2] | adst f32[N*2] |
  //     rowptr[pad(N+1)] | srt[E] | buf[E] |
  //     bucketCnt[1024] | bucketBase[1025] | bucketRes[1024]   (ints)
  char* wsb = (char*)d_ws;
  float*  obuf = (float*)wsb;
  __half* h16  = (__half*)(obuf + (size_t)N * 128);
  __half* h16b = h16 + (size_t)N * 128;
  float*  asrc = (float*)(h16b + (size_t)N * 40);
  float*  adst = asrc + (size_t)N * 2;
  int* rowptr  = (int*)(adst + (size_t)N * 2);
  int* srt     = rowptr + ((N + 1 + 7) & ~7);
  int* buf     = srt + E;
  int* bucketCnt  = buf + E;
  int* bucketBase = bucketCnt + 1024;
  int* bucketRes  = bucketBase + 1025;

  dim3 blk(256);
  int g_lin  = (N + 63) / 64;
  int g_wave = (N + 3) / 4;                 // 1 wave per node
  int g_bkt  = (E + EPB - 1) / EPB;         // 391 for E=1.6M

  // ---- bucketed CSR build (edge list identical across layers) ----
  k_zero<<<1, 1024, 0, stream>>>(bucketCnt, NB);
  k_bhist<<<g_bkt, blk, 0, stream>>>(ei, bucketCnt, E, NB);
  k_bscan<<<1, 1024, 0, stream>>>(bucketCnt, bucketBase, bucketRes,
                                  rowptr + N, NB);
  k_bucket<<<g_bkt, blk, 0, stream>>>(ei, bucketRes, buf, E, NB);
  k_fine<<<NB, blk, 0, stream>>>(bucketBase, buf, rowptr, srt, N);

  // ---------------- layer 0 ----------------
  k_linear128f<<<g_lin, blk, 0, stream>>>(x, W0, as0, ad0, h16, asrc, adst, N);
  k_agg128<<<g_wave, blk, 0, stream>>>(rowptr, srt, h16, asrc, adst, b0, obuf, N);

  // ---------------- layer 1 ----------------
  k_linear128f<<<g_lin, blk, 0, stream>>>(obuf, W1, as1, ad1, h16, asrc, adst, N);
  k_agg128<<<g_wave, blk, 0, stream>>>(rowptr, srt, h16, asrc, adst, b1, obuf, N);

  // ---------------- layer 2 ----------------
  k_linear40f<<<g_lin, blk, 0, stream>>>(obuf, W2, as2, ad2, h16b, asrc, adst, N);
  k_agg40<<<g_wave, blk, 0, stream>>>(rowptr, srt, h16b, asrc, adst, b2, out, N);
}